// Round 10
// baseline (205.339 us; speedup 1.0000x reference)
//
#include <hip/hip_runtime.h>
#include <math.h>
#include <stdint.h>

#define B_ 16
#define L_ 512
#define IN_ 64
#define D_ 64
#define LP_ 8

#define LN_EPS 1e-5f
#define EPSF 1e-8f

__device__ __forceinline__ float wredf(float v){
    #pragma unroll
    for (int o = 32; o; o >>= 1) v += __shfl_xor(v, o, 64);
    return v;
}
__device__ __forceinline__ double wredd(double v){
    #pragma unroll
    for (int o = 32; o; o >>= 1) v += __shfl_xor(v, o, 64);
    return v;
}

// async global->LDS (fallback k4 only)
__device__ __forceinline__ void gl_lds4(const float* gsrc, float* ldst){
    __builtin_amdgcn_global_load_lds((const __attribute__((address_space(1))) void*)gsrc,
                                     (__attribute__((address_space(3))) void*)ldst, 4, 0, 0);
}

// ================= merged K0+K1: projections + chunk partials + prompt =================
// blocks 0..511: projection path (16 rows each, 4 rows/wave, weights read once per 4 rows)
// blocks 512..543: prompt path (old k1)
template<int LC, int NCH>
__global__ __launch_bounds__(256) void k0k1(
    const float* __restrict__ X,
    const float* __restrict__ Wq, const float* __restrict__ bq,
    const float* __restrict__ Wk, const float* __restrict__ bk,
    const float* __restrict__ Wv, const float* __restrict__ bv,
    float* __restrict__ Q, float* __restrict__ Z, float* __restrict__ V,
    float* __restrict__ spart, float* __restrict__ zpart,
    double* __restrict__ qstats, unsigned int* __restrict__ cnt,
    const float* __restrict__ Pm, const float* __restrict__ Sm,
    const float* __restrict__ z_g, const float* __restrict__ z_b,
    const float* __restrict__ s_g, const float* __restrict__ s_b,
    const float* __restrict__ nam_g, const float* __restrict__ nam_b,
    const int* __restrict__ user_id,
    const float* __restrict__ prev_z_buf, const float* __restrict__ prev_s_buf,
    float* __restrict__ Pz, float* __restrict__ Ps, float* __restrict__ prevLN)
{
    __shared__ float sW[3][IN_*D_];     // 48 KB
    __shared__ float sx[16][IN_];       // 4 KB
    __shared__ float sz[16][D_], sv[16][D_]; // 8 KB
    __shared__ double l2d[4][2];
    __shared__ float sca[1];
    int bid = blockIdx.x;
    int t = threadIdx.x, p = t & 63, g = t >> 6;

    if (bid >= 512){
        // ---------------- prompt path (old k1) ----------------
        int blk = bid - 512; int b = blk & (B_-1); int path = blk >> 4;
        const float* Xs = (path ? Sm : Pm) + (size_t)b*LP_*IN_;
        for (int idx = t; idx < 2*LP_*D_; idx += 256){
            int which = idx >> 9;
            int j = (idx >> 6) & 7;
            int d = idx & 63;
            const float* W = which ? Wv : Wk;
            float acc = which ? bv[d] : bk[d];
            const float* xr = Xs + j*IN_;
            #pragma unroll
            for (int i = 0; i < IN_; i++) acc = fmaf(xr[i], W[i*D_+d], acc);
            if (!which) acc = acc > 0.f ? acc : (expf(acc)-1.f);
            if (which) sv[j][d] = acc; else sz[j][d] = acc;
        }
        __syncthreads();
        if (t < 64){
            float zc = 0.f;
            #pragma unroll
            for (int j = 0; j < LP_; j++) zc += sz[j][t];
            double s1 = wredd((double)zc), s2 = wredd((double)zc*(double)zc);
            float mz = (float)(s1*(1.0/64));
            float vz = (float)(s2*(1.0/64) - (s1*(1.0/64))*(s1*(1.0/64)));
            float zf = fmaf((zc-mz)*rsqrtf(vz+LN_EPS), z_g[t], z_b[t]);
            if (path == 0){ Pz[b*D_+t] = zf; }
            else {
                int uid = user_id[b];
                float pz = prev_z_buf[(size_t)uid*D_+t] + zf;
                float rr = wredf(pz*pz);
                if (t == 0) sca[0] = fmaxf(sqrtf(rr), 1e-8f) + EPSF;
            }
        }
        float sc[16];
        #pragma unroll
        for (int i = 0; i < 16; i++){
            int d = g*16 + i; float a = 0.f;
            #pragma unroll
            for (int j = 0; j < LP_; j++) a = fmaf(sz[j][d], sv[j][p], a);
            sc[i] = a;
        }
        double m0 = 0, m1 = 0;
        #pragma unroll
        for (int i = 0; i < 16; i++){ double a = sc[i]; m0 += a; m1 += a*a; }
        m0 = wredd(m0); m1 = wredd(m1);
        __syncthreads();
        if (p == 0){ l2d[g][0] = m0; l2d[g][1] = m1; }
        __syncthreads();
        m0 = l2d[0][0]+l2d[1][0]+l2d[2][0]+l2d[3][0];
        m1 = l2d[0][1]+l2d[1][1]+l2d[2][1]+l2d[3][1];
        double mean1 = m0*(1.0/4096.0);
        double var1 = m1*(1.0/4096.0) - mean1*mean1;
        float inv1 = rsqrtf((float)var1 + LN_EPS);
        float mean1f = (float)mean1;
        float sl[16];
        #pragma unroll
        for (int i = 0; i < 16; i++){
            int e = (g*16+i)*D_ + p;
            sl[i] = fmaf((sc[i]-mean1f)*inv1, s_g[e], s_b[e]);
        }
        if (path == 0){
            #pragma unroll
            for (int i = 0; i < 16; i++) Ps[(size_t)b*4096 + (g*16+i)*D_ + p] = sl[i];
            return;
        }
        int uid = user_id[b];
        float denom = sca[0];
        float pn[16]; double n0 = 0, n1 = 0;
        #pragma unroll
        for (int i = 0; i < 16; i++){
            int e = (g*16+i)*D_ + p;
            float ps = prev_s_buf[(size_t)uid*4096 + e] + sl[i];
            float v = ps / denom;
            pn[i] = v; n0 += v; n1 += (double)v*(double)v;
        }
        n0 = wredd(n0); n1 = wredd(n1);
        __syncthreads();
        if (p == 0){ l2d[g][0] = n0; l2d[g][1] = n1; }
        __syncthreads();
        n0 = l2d[0][0]+l2d[1][0]+l2d[2][0]+l2d[3][0];
        n1 = l2d[0][1]+l2d[1][1]+l2d[2][1]+l2d[3][1];
        double meanp = n0*(1.0/4096.0);
        double varp = n1*(1.0/4096.0) - meanp*meanp;
        float invp = rsqrtf((float)varp + LN_EPS);
        float meanpf = (float)meanp;
        #pragma unroll
        for (int i = 0; i < 16; i++){
            int e = (g*16+i)*D_ + p;
            prevLN[(size_t)b*4096 + e] = fmaf((pn[i]-meanpf)*invp, nam_g[e], nam_b[e]);
        }
        return;
    }

    // ---------------- projection path ----------------
    if (bid == 0){
        if (t < 2) qstats[t] = 0.0;
        if (t == 2) *cnt = 0u;
    }
    int r0 = bid * 16;
    // stage weights (coalesced) and 16 X rows
    for (int k = t; k < IN_*D_; k += 256){ sW[0][k]=Wq[k]; sW[1][k]=Wk[k]; sW[2][k]=Wv[k]; }
    for (int k = t; k < 16*IN_; k += 256) sx[k>>6][k&63] = X[(size_t)(r0 + (k>>6))*IN_ + (k&63)];
    __syncthreads();
    float aq[4], ak[4], av[4];
    float bqv = bq[p], bkv = bk[p], bvv = bv[p];
    #pragma unroll
    for (int r = 0; r < 4; r++){ aq[r]=bqv; ak[r]=bkv; av[r]=bvv; }
    #pragma unroll
    for (int i = 0; i < IN_; i++){
        float wqv = sW[0][i*D_+p], wkv = sW[1][i*D_+p], wvv = sW[2][i*D_+p];
        #pragma unroll
        for (int r = 0; r < 4; r++){
            float x = sx[g*4+r][i];
            aq[r] = fmaf(x, wqv, aq[r]);
            ak[r] = fmaf(x, wkv, ak[r]);
            av[r] = fmaf(x, wvv, av[r]);
        }
    }
    #pragma unroll
    for (int r = 0; r < 4; r++){
        int lrow = g*4 + r;
        size_t row = r0 + lrow;
        float q = aq[r] > 0.f ? aq[r] : (expf(aq[r])-1.f);
        float z = ak[r] > 0.f ? ak[r] : (expf(ak[r])-1.f);
        Q[row*D_+p] = q; Z[row*D_+p] = z; V[row*D_+p] = av[r];
        sz[lrow][p] = z; sv[lrow][p] = av[r];
    }
    __syncthreads();
    int b = r0 >> 9;
    int c0 = (r0 & 511) / LC;
    #pragma unroll
    for (int ch = 0; ch < NCH; ch++){
        float acc[16];
        #pragma unroll
        for (int i = 0; i < 16; i++) acc[i] = 0.f;
        #pragma unroll
        for (int l = 0; l < LC; l++){
            float vv = sv[ch*LC+l][p];
            #pragma unroll
            for (int i = 0; i < 16; i++) acc[i] = fmaf(sz[ch*LC+l][g*16+i], vv, acc[i]);
        }
        size_t cg = (size_t)(b*(512/LC) + c0 + ch);
        size_t base = cg << 12;
        #pragma unroll
        for (int i = 0; i < 16; i++) spart[base + (g*16+i)*64 + p] = acc[i];
        if (g == 0){
            float za = 0.f;
            #pragma unroll
            for (int l = 0; l < LC; l++) za += sz[ch*LC+l][p];
            zpart[cg*64 + p] = za;
        }
    }
}

// ================= K3: register-array exclusive scan over chunks =================
template<int C>
__global__ __launch_bounds__(256) void k3_scan(
    float* __restrict__ spart, float* __restrict__ zpart)
{
    int id = blockIdx.x*256 + threadIdx.x;
    const int NS = B_*4096;
    if (id < NS){
        int b = id >> 12, e = id & 4095;
        float a[C];
        #pragma unroll
        for (int c = 0; c < C; c++) a[c] = spart[(((size_t)(b*C+c)) << 12) + e];
        float run = 0.f;
        #pragma unroll
        for (int c = 0; c < C; c++){ float tv = a[c]; a[c] = run; run += tv; }
        #pragma unroll
        for (int c = 0; c < C; c++) spart[(((size_t)(b*C+c)) << 12) + e] = a[c];
    } else if (id < NS + B_*64){
        int k = id - NS;
        int b = k >> 6, d = k & 63;
        float a[C];
        #pragma unroll
        for (int c = 0; c < C; c++) a[c] = zpart[(size_t)(b*C+c)*64 + d];
        float run = 0.f;
        #pragma unroll
        for (int c = 0; c < C; c++){ float tv = a[c]; a[c] = run; run += tv; }
        #pragma unroll
        for (int c = 0; c < C; c++) zpart[(size_t)(b*C+c)*64 + d] = a[c];
    }
}

// ================= K4 fused: parallel prologue + light scan loop + epilogue + std =================
__global__ __launch_bounds__(256, 4) void k4_fused(
    const float* __restrict__ Q, const float* __restrict__ Z, const float* __restrict__ V,
    const float* __restrict__ spart, const float* __restrict__ zpart,
    const float* __restrict__ Pz, const float* __restrict__ Ps,
    const float* __restrict__ prevLN,
    const float* __restrict__ z_g, const float* __restrict__ z_b,
    const float* __restrict__ s_g, const float* __restrict__ s_b,
    const float* __restrict__ nam_g, const float* __restrict__ nam_b,
    const float* __restrict__ na_g, const float* __restrict__ na_b,
    float* __restrict__ out, double* __restrict__ qstats,
    unsigned int* __restrict__ cnt, int outIdx)
{
    const int C_ = 64, LC = 8;
    int wg = blockIdx.x; int b = wg >> 6, c = wg & 63;
    int t = threadIdx.x, g = t >> 6, p = t & 63;
    __shared__ float lzall[LC][64], lvall[LC][64], lqall[LC][64]; // staged rows
    __shared__ float lnqall[LC][64];     // normalized q per step
    __shared__ float lnaAll[LC][4][64];  // per-wave na partials (deferred out-LN)
    __shared__ float lmd[2][4][6];
    __shared__ float lcs[4][5];
    __shared__ float lrA[LC];
    __shared__ double qpart[4][2];
    float A[16], Gv[16], Bv[16], NGv[16], NBv[16];
    size_t sbase = ((size_t)wg) << 12;
    size_t bbase = ((size_t)b) << 12;
    size_t row0 = (size_t)b*L_ + (size_t)c*LC;

    // stage all LC rows of Z,V,Q
    for (int k = t; k < 3*LC*64; k += 256){
        int arr = k / (LC*64);
        int idx = k - arr*(LC*64);
        int row = idx >> 6, col = idx & 63;
        float v = (arr==0 ? Z : (arr==1 ? V : Q))[(row0+row)*64 + col];
        if (arr == 0) lzall[row][col] = v;
        else if (arr == 1) lvall[row][col] = v;
        else lqall[row][col] = v;
    }
    #pragma unroll
    for (int i = 0; i < 16; i++){
        int e = (g*16+i)*64 + p;
        A[i]   = spart[sbase + e];
        Gv[i]  = s_g[e];
        Bv[i]  = s_b[e] + Ps[bbase + e];
        NGv[i] = nam_g[e];
        NBv[i] = nam_b[e] + prevLN[bbase + e];
    }
    float zcum = zpart[(size_t)wg*64 + p];
    float zgr = z_g[p], zbr = z_b[p], Pzv = Pz[b*64 + p];
    __syncthreads();   // staging visible

    // ---- parallel prologue: wave g owns steps 2g, 2g+1 ----
    {
        int l0 = 2*g;
        float zc = zcum;
        for (int j = 0; j <= l0; j++) zc += lzall[j][p];
        double qs = 0.0, qs2 = 0.0;
        #pragma unroll
        for (int s = 0; s < 2; s++){
            int l = l0 + s;
            if (s == 1) zc += lzall[l][p];
            float s1 = wredf(zc), s2 = wredf(zc*zc);
            float mz = s1*(1.f/64.f);
            float vz = s2*(1.f/64.f) - mz*mz;
            float zf = fmaf((zc-mz)*rsqrtf(vz+LN_EPS), zgr, zbr) + Pzv;
            float rr = wredf(zf*zf);
            if (p == 0) lrA[l] = fmaxf(sqrtf(rr), 1e-8f);
            float qv = lqall[l][p];
            float qq = wredf(qv*qv);
            lnqall[l][p] = qv / fmaxf(sqrtf(qq), 1e-8f);
            float qn = qv / fmaxf(zf, 1e-6f);
            qs += (double)qn; qs2 += (double)qn*(double)qn;
        }
        qs = wredd(qs); qs2 = wredd(qs2);
        if (p == 0){ qpart[g][0] = qs; qpart[g][1] = qs2; }
    }
    // block constants over the (G, B) tile
    {
        float cs0=0,cs1=0,cs2=0,cs3=0,cs4=0;
        #pragma unroll
        for (int i = 0; i < 16; i++){
            float gd = Gv[i], bd = Bv[i];
            cs0 += gd; cs1 += gd*gd; cs2 += bd; cs3 += bd*bd; cs4 += gd*bd;
        }
        cs0=wredf(cs0); cs1=wredf(cs1); cs2=wredf(cs2); cs3=wredf(cs3); cs4=wredf(cs4);
        if (p == 0){ lcs[g][0]=cs0; lcs[g][1]=cs1; lcs[g][2]=cs2; lcs[g][3]=cs3; lcs[g][4]=cs4; }
    }
    __syncthreads();   // lcs/lrA/lnqall visible
    float Cg  = lcs[0][0]+lcs[1][0]+lcs[2][0]+lcs[3][0];
    float Cg2 = lcs[0][1]+lcs[1][1]+lcs[2][1]+lcs[3][1];
    float Cb  = lcs[0][2]+lcs[1][2]+lcs[2][2]+lcs[3][2];
    float Cb2 = lcs[0][3]+lcs[1][3]+lcs[2][3]+lcs[3][3];
    float Cgb = lcs[0][4]+lcs[1][4]+lcs[2][4]+lcs[3][4];

    const float INV = 1.f/4096.f;
    // ---- main scan loop: 1 barrier/step, no serial chains except the 6-moment reduce ----
    for (int l = 0; l < LC; ++l){
        int cur = l & 1;
        float m0=0,m1=0,m2=0,m3=0,m4=0,m5=0;
        float vp = lvall[l][p];
        #pragma unroll
        for (int i = 0; i < 16; i++){
            A[i] = fmaf(lzall[l][g*16+i], vp, A[i]);
            float a = A[i];
            m0 += a; m1 = fmaf(a, a, m1);
            float tt = a * Gv[i];
            m2 += tt; m5 = fmaf(tt, tt, m5); m3 = fmaf(tt, Gv[i], m3); m4 = fmaf(tt, Bv[i], m4);
        }
        m0=wredf(m0); m1=wredf(m1); m2=wredf(m2); m3=wredf(m3); m4=wredf(m4); m5=wredf(m5);
        if (p == 0){
            lmd[cur][g][0]=m0; lmd[cur][g][1]=m1; lmd[cur][g][2]=m2;
            lmd[cur][g][3]=m3; lmd[cur][g][4]=m4; lmd[cur][g][5]=m5;
        }
        __syncthreads();
        float M0 = lmd[cur][0][0]+lmd[cur][1][0]+lmd[cur][2][0]+lmd[cur][3][0];
        float M1 = lmd[cur][0][1]+lmd[cur][1][1]+lmd[cur][2][1]+lmd[cur][3][1];
        float M2 = lmd[cur][0][2]+lmd[cur][1][2]+lmd[cur][2][2]+lmd[cur][3][2];
        float M3 = lmd[cur][0][3]+lmd[cur][1][3]+lmd[cur][2][3]+lmd[cur][3][3];
        float M4 = lmd[cur][0][4]+lmd[cur][1][4]+lmd[cur][2][4]+lmd[cur][3][4];
        float M5 = lmd[cur][0][5]+lmd[cur][1][5]+lmd[cur][2][5]+lmd[cur][3][5];
        float meanA = M0*INV;
        float varA  = M1*INV - meanA*meanA;
        float inv1 = rsqrtf(varA + LN_EPS);
        float sum_sf = inv1*(M2 - meanA*Cg) + Cb;
        float ssq_sf = inv1*inv1*(M5 - 2.f*meanA*M3 + meanA*meanA*Cg2)
                     + 2.f*inv1*(M4 - meanA*Cgb) + Cb2;
        float invr = 1.f / lrA[l];
        float mean_sf = sum_sf*INV;
        float var_sf  = ssq_sf*INV - mean_sf*mean_sf;
        float mean_nam = mean_sf * invr;
        float var_nam  = var_sf * invr * invr;
        float inv2 = rsqrtf(var_nam + LN_EPS);
        float nal = 0.f;
        #pragma unroll
        for (int i = 0; i < 16; i++){
            float sf = fmaf((A[i]-meanA)*inv1, Gv[i], Bv[i]);
            float nm = sf*invr;
            float elem = fmaf((nm-mean_nam)*inv2, NGv[i], NBv[i]);
            nal = fmaf(lnqall[l][g*16+i], elem, nal);
        }
        lnaAll[l][g][p] = nal;
    }
    __syncthreads();   // lnaAll complete

    // ---- epilogue: out-LN parallel across waves (2 rows each) ----
    {
        float nagr = na_g[p], nabr = na_b[p];
        #pragma unroll
        for (int s = 0; s < 2; s++){
            int l = 2*g + s;
            float nt = lnaAll[l][0][p]+lnaAll[l][1][p]+lnaAll[l][2][p]+lnaAll[l][3][p];
            float s1 = wredf(nt), s2 = wredf(nt*nt);
            float mu = s1*(1.f/64.f);
            float va = s2*(1.f/64.f) - mu*mu;
            out[(row0+l)*64 + p] = fmaf((nt-mu)*rsqrtf(va+LN_EPS), nagr, nabr);
        }
    }
    // ---- std: per-block atomics + completion counter (replaces k5) ----
    if (t == 0){
        double S  = qpart[0][0]+qpart[1][0]+qpart[2][0]+qpart[3][0];
        double S2 = qpart[0][1]+qpart[1][1]+qpart[2][1]+qpart[3][1];
        atomicAdd(&qstats[0], S);
        atomicAdd(&qstats[1], S2);
        __threadfence();
        unsigned int old = atomicAdd(cnt, 1u);
        if (old == (unsigned int)(B_*C_ - 1)){
            __threadfence();
            double sD  = *((volatile double*)&qstats[0]);
            double sqD = *((volatile double*)&qstats[1]);
            const double N = (double)(B_*L_*D_);
            double var = (sqD - sD*sD/N) / (N - 1.0);
            out[outIdx] = (float)sqrt(var > 0.0 ? var : 0.0);
        }
    }
}

// ================= fallback path (small workspace): old kernels =================
__global__ __launch_bounds__(256) void k0_qzv(
    const float* __restrict__ X,
    const float* __restrict__ Wq, const float* __restrict__ bq,
    const float* __restrict__ Wk, const float* __restrict__ bk,
    const float* __restrict__ Wv, const float* __restrict__ bv,
    float* __restrict__ Q, float* __restrict__ Z, float* __restrict__ V,
    double* __restrict__ qstats)
{
    __shared__ float sW[3][IN_*D_];
    __shared__ float sx[4][IN_];
    int t = threadIdx.x;
    if (blockIdx.x == 0 && t < 2) qstats[t] = 0.0;
    for (int i = t; i < IN_*D_; i += 256){ sW[0][i]=Wq[i]; sW[1][i]=Wk[i]; sW[2][i]=Wv[i]; }
    int p = t & 63, lr = t >> 6;
    float bqv = bq[p], bkv = bk[p], bvv = bv[p];
    for (int it = 0; it < 4; ++it){
        int r0 = blockIdx.x*16 + it*4;
        __syncthreads();
        for (int i = t; i < 4*IN_; i += 256)
            sx[i>>6][i&63] = X[(size_t)(r0 + (i>>6))*IN_ + (i&63)];
        __syncthreads();
        size_t row = r0 + lr;
        float aq = bqv, ak = bkv, av = bvv;
        #pragma unroll
        for (int i = 0; i < IN_; i++){
            float x = sx[lr][i];
            aq = fmaf(x, sW[0][i*D_+p], aq);
            ak = fmaf(x, sW[1][i*D_+p], ak);
            av = fmaf(x, sW[2][i*D_+p], av);
        }
        Q[row*D_+p] = aq > 0.f ? aq : (expf(aq)-1.f);
        Z[row*D_+p] = ak > 0.f ? ak : (expf(ak)-1.f);
        V[row*D_+p] = av;
    }
}

__global__ __launch_bounds__(256) void k1_prompt(
    const float* __restrict__ Pm, const float* __restrict__ Sm,
    const float* __restrict__ Wk, const float* __restrict__ bk,
    const float* __restrict__ Wv, const float* __restrict__ bv,
    const float* __restrict__ z_g, const float* __restrict__ z_b,
    const float* __restrict__ s_g, const float* __restrict__ s_b,
    const float* __restrict__ nam_g, const float* __restrict__ nam_b,
    const int* __restrict__ user_id,
    const float* __restrict__ prev_z_buf, const float* __restrict__ prev_s_buf,
    float* __restrict__ Pz, float* __restrict__ Ps, float* __restrict__ prevLN)
{
    __shared__ float sz[LP_][D_], sv[LP_][D_];
    __shared__ double lds[4][2];
    __shared__ float sca[1];
    int blk = blockIdx.x; int b = blk & (B_-1); int path = blk >> 4;
    int t = threadIdx.x, g = t >> 6, p = t & 63;
    const float* Xs = (path ? Sm : Pm) + (size_t)b*LP_*IN_;
    for (int idx = t; idx < 2*LP_*D_; idx += 256){
        int which = idx >> 9;
        int j = (idx >> 6) & 7;
        int d = idx & 63;
        const float* W = which ? Wv : Wk;
        float acc = which ? bv[d] : bk[d];
        const float* xr = Xs + j*IN_;
        #pragma unroll
        for (int i = 0; i < IN_; i++) acc = fmaf(xr[i], W[i*D_+d], acc);
        if (!which) acc = acc > 0.f ? acc : (expf(acc)-1.f);
        if (which) sv[j][d] = acc; else sz[j][d] = acc;
    }
    __syncthreads();
    if (t < 64){
        float zc = 0.f;
        #pragma unroll
        for (int j = 0; j < LP_; j++) zc += sz[j][t];
        double s1 = wredd((double)zc), s2 = wredd((double)zc*(double)zc);
        float mz = (float)(s1*(1.0/64));
        float vz = (float)(s2*(1.0/64) - (s1*(1.0/64))*(s1*(1.0/64)));
        float zf = fmaf((zc-mz)*rsqrtf(vz+LN_EPS), z_g[t], z_b[t]);
        if (path == 0){ Pz[b*D_+t] = zf; }
        else {
            int uid = user_id[b];
            float pz = prev_z_buf[(size_t)uid*D_+t] + zf;
            float rr = wredf(pz*pz);
            if (t == 0) sca[0] = fmaxf(sqrtf(rr), 1e-8f) + EPSF;
        }
    }
    float sc[16];
    #pragma unroll
    for (int i = 0; i < 16; i++){
        int d = g*16 + i; float a = 0.f;
        #pragma unroll
        for (int j = 0; j < LP_; j++) a = fmaf(sz[j][d], sv[j][p], a);
        sc[i] = a;
    }
    double m0 = 0, m1 = 0;
    #pragma unroll
    for (int i = 0; i < 16; i++){ double a = sc[i]; m0 += a; m1 += a*a; }
    m0 = wredd(m0); m1 = wredd(m1);
    __syncthreads();
    if (p == 0){ lds[g][0] = m0; lds[g][1] = m1; }
    __syncthreads();
    m0 = lds[0][0]+lds[1][0]+lds[2][0]+lds[3][0];
    m1 = lds[0][1]+lds[1][1]+lds[2][1]+lds[3][1];
    double mean1 = m0*(1.0/4096.0);
    double var1 = m1*(1.0/4096.0) - mean1*mean1;
    float inv1 = rsqrtf((float)var1 + LN_EPS);
    float mean1f = (float)mean1;
    float sl[16];
    #pragma unroll
    for (int i = 0; i < 16; i++){
        int e = (g*16+i)*D_ + p;
        sl[i] = fmaf((sc[i]-mean1f)*inv1, s_g[e], s_b[e]);
    }
    if (path == 0){
        #pragma unroll
        for (int i = 0; i < 16; i++) Ps[(size_t)b*4096 + (g*16+i)*D_ + p] = sl[i];
        return;
    }
    int uid = user_id[b];
    float denom = sca[0];
    float pn[16]; double n0 = 0, n1 = 0;
    #pragma unroll
    for (int i = 0; i < 16; i++){
        int e = (g*16+i)*D_ + p;
        float ps = prev_s_buf[(size_t)uid*4096 + e] + sl[i];
        float v = ps / denom;
        pn[i] = v; n0 += v; n1 += (double)v*(double)v;
    }
    n0 = wredd(n0); n1 = wredd(n1);
    __syncthreads();
    if (p == 0){ lds[g][0] = n0; lds[g][1] = n1; }
    __syncthreads();
    n0 = lds[0][0]+lds[1][0]+lds[2][0]+lds[3][0];
    n1 = lds[0][1]+lds[1][1]+lds[2][1]+lds[3][1];
    double meanp = n0*(1.0/4096.0);
    double varp = n1*(1.0/4096.0) - meanp*meanp;
    float invp = rsqrtf((float)varp + LN_EPS);
    float meanpf = (float)meanp;
    #pragma unroll
    for (int i = 0; i < 16; i++){
        int e = (g*16+i)*D_ + p;
        prevLN[(size_t)b*4096 + e] = fmaf((pn[i]-meanpf)*invp, nam_g[e], nam_b[e]);
    }
}

__global__ __launch_bounds__(256) void k2_chunks(
    const float* __restrict__ Z, const float* __restrict__ V,
    float* __restrict__ spart, float* __restrict__ zpart, int C_, int LC_)
{
    int wg = blockIdx.x; int b = wg / C_, c = wg - b*C_;
    int t = threadIdx.x, g = t >> 6, p = t & 63;
    __shared__ float lz[64], lv[64];
    float acc[16];
    #pragma unroll
    for (int i = 0; i < 16; i++) acc[i] = 0.f;
    float zacc = 0.f;
    for (int l = 0; l < LC_; l++){
        size_t row = (size_t)b*L_ + c*LC_ + l;
        __syncthreads();
        if (t < 64) lz[t] = Z[row*64 + t];
        else if (t < 128) lv[t-64] = V[row*64 + (t-64)];
        __syncthreads();
        float v = lv[p];
        #pragma unroll
        for (int i = 0; i < 16; i++) acc[i] = fmaf(lz[g*16+i], v, acc[i]);
        if (t < 64) zacc += lz[t];
    }
    size_t base = ((size_t)wg) << 12;
    #pragma unroll
    for (int i = 0; i < 16; i++) spart[base + (g*16+i)*64 + p] = acc[i];
    if (t < 64) zpart[(size_t)wg*64 + t] = zacc;
}

__global__ __launch_bounds__(256) void k3_serial(
    float* __restrict__ spart, float* __restrict__ zpart, int C_)
{
    int id = blockIdx.x*256 + threadIdx.x;
    const int NS = B_*4096;
    if (id < NS){
        int b = id >> 12;
        int e = id & 4095;
        float run = 0.f;
        for (int c = 0; c < C_; ++c){
            float* ptr = spart + (((size_t)(b*C_+c)) << 12) + e;
            float tv = *ptr; *ptr = run; run += tv;
        }
    } else if (id < NS + B_*64){
        int k = id - NS;
        int b = k >> 6, d = k & 63;
        float run = 0.f;
        for (int c = 0; c < C_; ++c){
            float* ptr = zpart + (size_t)(b*C_+c)*64 + d;
            float tv = *ptr; *ptr = run; run += tv;
        }
    }
}

__global__ __launch_bounds__(256) void k4_main(
    const float* __restrict__ Q, const float* __restrict__ Z, const float* __restrict__ V,
    const float* __restrict__ spart, const float* __restrict__ zpart,
    const float* __restrict__ Pz, const float* __restrict__ Ps,
    const float* __restrict__ prevLN,
    const float* __restrict__ z_g, const float* __restrict__ z_b,
    const float* __restrict__ s_g, const float* __restrict__ s_b,
    const float* __restrict__ nam_g, const float* __restrict__ nam_b,
    const float* __restrict__ na_g, const float* __restrict__ na_b,
    float* __restrict__ out, double* qstats, int C_, int LC_)
{
    int wg = blockIdx.x; int b = wg / C_, c = wg - b*C_;
    int t = threadIdx.x, g = t >> 6, p = t & 63;
    __shared__ float lz[2][64], lv[2][64], lqb[2][64], lnq[2][64];
    __shared__ float lna[2][4][64];
    __shared__ float lmd[2][4][6];
    __shared__ float lcs[4][5];
    __shared__ float lr[2];
    __shared__ float lPz[64];
    float A[16], Gv[16], Bv[16], NGv[16], NBv[16];
    size_t sbase = ((size_t)wg) << 12;
    size_t bbase = ((size_t)b) << 12;
    size_t row0 = (size_t)b*L_ + (size_t)c*LC_;
    if (g == 1) gl_lds4(Q + row0*64 + p, &lqb[0][0]);
    else if (g == 2) gl_lds4(Z + row0*64 + p, &lz[0][0]);
    else if (g == 3) gl_lds4(V + row0*64 + p, &lv[0][0]);
    #pragma unroll
    for (int i = 0; i < 16; i++){
        int e = (g*16+i)*64 + p;
        A[i]   = spart[sbase + e];
        Gv[i]  = s_g[e];
        Bv[i]  = s_b[e] + Ps[bbase + e];
        NGv[i] = nam_g[e];
        NBv[i] = nam_b[e] + prevLN[bbase + e];
    }
    float cs0=0,cs1=0,cs2=0,cs3=0,cs4=0;
    #pragma unroll
    for (int i = 0; i < 16; i++){
        float gd = Gv[i], bd = Bv[i];
        cs0 += gd; cs1 += gd*gd; cs2 += bd; cs3 += bd*bd; cs4 += gd*bd;
    }
    cs0=wredf(cs0); cs1=wredf(cs1); cs2=wredf(cs2); cs3=wredf(cs3); cs4=wredf(cs4);
    if (p == 0){ lcs[g][0]=cs0; lcs[g][1]=cs1; lcs[g][2]=cs2; lcs[g][3]=cs3; lcs[g][4]=cs4; }
    float zc=0.f, zgr=0.f, zbr=0.f, nagr=0.f, nabr=0.f;
    if (g == 0){
        zc = zpart[(size_t)wg*64 + p];
        lPz[p] = Pz[b*64 + p];
        zgr = z_g[p]; zbr = z_b[p];
    }
    if (g == 3){ nagr = na_g[p]; nabr = na_b[p]; }
    __syncthreads();
    float Cg  = lcs[0][0]+lcs[1][0]+lcs[2][0]+lcs[3][0];
    float Cg2 = lcs[0][1]+lcs[1][1]+lcs[2][1]+lcs[3][1];
    float Cb  = lcs[0][2]+lcs[1][2]+lcs[2][2]+lcs[3][2];
    float Cb2 = lcs[0][3]+lcs[1][3]+lcs[2][3]+lcs[3][3];
    float Cgb = lcs[0][4]+lcs[1][4]+lcs[2][4]+lcs[3][4];

    double qsum = 0.0, qsq = 0.0;
    const float INV = 1.f/4096.f;
    for (int ll = 0; ll < LC_; ++ll){
        int cur = ll & 1, nxt = cur ^ 1, prv = cur ^ 1;
        size_t row = row0 + ll;
        if (ll + 1 < LC_){
            if (g == 1) gl_lds4(Q + (row+1)*64 + p, &lqb[nxt][0]);
            else if (g == 2) gl_lds4(Z + (row+1)*64 + p, &lz[nxt][0]);
            else if (g == 3) gl_lds4(V + (row+1)*64 + p, &lv[nxt][0]);
        }
        if (g == 0){
            float zl = lz[cur][p]; zc += zl;
            float s1 = wredf(zc), s2 = wredf(zc*zc);
            float mz = s1*(1.f/64.f);
            float vz = s2*(1.f/64.f) - mz*mz;
            float zf = fmaf((zc-mz)*rsqrtf(vz+LN_EPS), zgr, zbr) + lPz[p];
            float rr = wredf(zf*zf);
            if (p == 0) lr[cur] = fmaxf(sqrtf(rr), 1e-8f);
            float qvv = lqb[cur][p];
            float qn = qvv / fmaxf(zf, 1e-6f);
            qsum += (double)qn; qsq += (double)qn*(double)qn;
        }
        if (g == 1){
            float qvv = lqb[cur][p];
            float qq = wredf(qvv*qvv);
            lnq[cur][p] = qvv / fmaxf(sqrtf(qq), 1e-8f);
        }
        float m0=0,m1=0,m2=0,m3=0,m4=0,m5=0;
        float vp = lv[cur][p];
        #pragma unroll
        for (int i = 0; i < 16; i++){
            A[i] = fmaf(lz[cur][g*16+i], vp, A[i]);
            float a = A[i];
            m0 += a; m1 = fmaf(a, a, m1);
            float tt = a * Gv[i];
            m2 += tt; m5 = fmaf(tt, tt, m5); m3 = fmaf(tt, Gv[i], m3); m4 = fmaf(tt, Bv[i], m4);
        }
        m0=wredf(m0); m1=wredf(m1); m2=wredf(m2); m3=wredf(m3); m4=wredf(m4); m5=wredf(m5);
        if (p == 0){
            lmd[cur][g][0]=m0; lmd[cur][g][1]=m1; lmd[cur][g][2]=m2;
            lmd[cur][g][3]=m3; lmd[cur][g][4]=m4; lmd[cur][g][5]=m5;
        }
        __syncthreads();
        float M0 = lmd[cur][0][0]+lmd[cur][1][0]+lmd[cur][2][0]+lmd[cur][3][0];
        float M1 = lmd[cur][0][1]+lmd[cur][1][1]+lmd[cur][2][1]+lmd[cur][3][1];
        float M2 = lmd[cur][0][2]+lmd[cur][1][2]+lmd[cur][2][2]+lmd[cur][3][2];
        float M3 = lmd[cur][0][3]+lmd[cur][1][3]+lmd[cur][2][3]+lmd[cur][3][3];
        float M4 = lmd[cur][0][4]+lmd[cur][1][4]+lmd[cur][2][4]+lmd[cur][3][4];
        float M5 = lmd[cur][0][5]+lmd[cur][1][5]+lmd[cur][2][5]+lmd[cur][3][5];
        float meanA = M0*INV;
        float varA  = M1*INV - meanA*meanA;
        float inv1 = rsqrtf(varA + LN_EPS);
        float sum_sf = inv1*(M2 - meanA*Cg) + Cb;
        float ssq_sf = inv1*inv1*(M5 - 2.f*meanA*M3 + meanA*meanA*Cg2)
                     + 2.f*inv1*(M4 - meanA*Cgb) + Cb2;
        float r = lr[cur];
        float invr = 1.f/r;
        float mean_sf = sum_sf*INV;
        float var_sf  = ssq_sf*INV - mean_sf*mean_sf;
        float mean_nam = mean_sf * invr;
        float var_nam  = var_sf * invr * invr;
        float inv2 = rsqrtf(var_nam + LN_EPS);
        float nal = 0.f;
        #pragma unroll
        for (int i = 0; i < 16; i++){
            float sf = fmaf((A[i]-meanA)*inv1, Gv[i], Bv[i]);
            float nm = sf*invr;
            float elem = fmaf((nm-mean_nam)*inv2, NGv[i], NBv[i]);
            nal = fmaf(lnq[cur][g*16+i], elem, nal);
        }
        lna[cur][g][p] = nal;
        if (g == 3 && ll > 0){
            float nt = lna[prv][0][p]+lna[prv][1][p]+lna[prv][2][p]+lna[prv][3][p];
            float s1 = wredf(nt), s2 = wredf(nt*nt);
            float mu = s1*(1.f/64.f);
            float va = s2*(1.f/64.f) - mu*mu;
            out[(row-1)*64 + p] = fmaf((nt-mu)*rsqrtf(va+LN_EPS), nagr, nabr);
        }
    }
    __syncthreads();
    if (g == 3){
        int lastc = (LC_-1) & 1;
        float nt = lna[lastc][0][p]+lna[lastc][1][p]+lna[lastc][2][p]+lna[lastc][3][p];
        float s1 = wredf(nt), s2 = wredf(nt*nt);
        float mu = s1*(1.f/64.f);
        float va = s2*(1.f/64.f) - mu*mu;
        out[(row0+LC_-1)*64 + p] = fmaf((nt-mu)*rsqrtf(va+LN_EPS), nagr, nabr);
    }
    if (g == 0){
        double s = wredd(qsum), s2 = wredd(qsq);
        if (p == 0){
            atomicAdd(&qstats[0], s);
            atomicAdd(&qstats[1], s2);
        }
    }
}

__global__ void k5_std(const double* __restrict__ qstats, float* __restrict__ out, int idx){
    if (threadIdx.x == 0 && blockIdx.x == 0){
        double s = qstats[0], sq = qstats[1];
        const double N = (double)(B_*L_*D_);
        double var = (sq - s*s/N) / (N - 1.0);
        out[idx] = (float)sqrt(var > 0.0 ? var : 0.0);
    }
}

extern "C" void kernel_launch(void* const* d_in, const int* in_sizes, int n_in,
                              void* d_out, int out_size, void* d_ws, size_t ws_size,
                              hipStream_t stream)
{
    (void)in_sizes; (void)n_in;
    const int*   user_id    = (const int*)d_in[0];
    const float* seqs       = (const float*)d_in[1];
    const float* Pm         = (const float*)d_in[2];
    const float* Sm         = (const float*)d_in[3];
    const float* Wq         = (const float*)d_in[4];
    const float* bq         = (const float*)d_in[5];
    const float* Wk         = (const float*)d_in[6];
    const float* bk         = (const float*)d_in[7];
    const float* Wv         = (const float*)d_in[8];
    const float* bv         = (const float*)d_in[9];
    const float* z_g        = (const float*)d_in[10];
    const float* z_b        = (const float*)d_in[11];
    const float* s_g        = (const float*)d_in[12];
    const float* s_b        = (const float*)d_in[13];
    const float* nam_g      = (const float*)d_in[14];
    const float* nam_b      = (const float*)d_in[15];
    const float* na_g       = (const float*)d_in[16];
    const float* na_b       = (const float*)d_in[17];
    const float* prev_z_buf = (const float*)d_in[18];
    const float* prev_s_buf = (const float*)d_in[19];
    float* out = (float*)d_out;

    char* w = (char*)d_ws;
    double* qstats = (double*)w;                     // 16 B
    unsigned int* cnt = (unsigned int*)(w + 16);     // 4 B (pad to 32)
    float* Q  = (float*)(w + 32);                    // 524288
    float* Zb = Q  + 524288;
    float* Vb = Zb + 524288;
    float* Pz = Vb + 524288;                         // 1024
    float* Ps = Pz + 1024;                           // 65536
    float* prevLN = Ps + 65536;                      // 65536
    float* spart  = prevLN + 65536;                  // 16*C*4096
    size_t fixedBytes = 32 + (size_t)(3*524288 + 1024 + 2*65536)*4;
    int C = 64;
    while (C > 1 && fixedBytes + (size_t)16*C*(4096+64)*4 > ws_size) C >>= 1;
    int LC = 512 / C;
    float* zpart = spart + (size_t)16*C*4096;

    if (C == 64){
        k0k1<8,2><<<544, 256, 0, stream>>>(seqs, Wq, bq, Wk, bk, Wv, bv,
                                           Q, Zb, Vb, spart, zpart, qstats, cnt,
                                           Pm, Sm, z_g, z_b, s_g, s_b, nam_g, nam_b,
                                           user_id, prev_z_buf, prev_s_buf,
                                           Pz, Ps, prevLN);
        k3_scan<64><<<(16*4096 + 16*64 + 255)/256, 256, 0, stream>>>(spart, zpart);
        k4_fused<<<16*64, 256, 0, stream>>>(Q, Zb, Vb, spart, zpart, Pz, Ps, prevLN,
                                            z_g, z_b, s_g, s_b, nam_g, nam_b, na_g, na_b,
                                            out, qstats, cnt, out_size - 1);
    } else {
        k0_qzv<<<512, 256, 0, stream>>>(seqs, Wq, bq, Wk, bk, Wv, bv, Q, Zb, Vb, qstats);
        k1_prompt<<<32, 256, 0, stream>>>(Pm, Sm, Wk, bk, Wv, bv, z_g, z_b, s_g, s_b,
                                          nam_g, nam_b, user_id, prev_z_buf, prev_s_buf,
                                          Pz, Ps, prevLN);
        k2_chunks<<<16*C, 256, 0, stream>>>(Zb, Vb, spart, zpart, C, LC);
        k3_serial<<<(16*4096 + 16*64 + 255)/256, 256, 0, stream>>>(spart, zpart, C);
        k4_main<<<16*C, 256, 0, stream>>>(Q, Zb, Vb, spart, zpart, Pz, Ps, prevLN,
                                          z_g, z_b, s_g, s_b, nam_g, nam_b, na_g, na_b,
                                          out, qstats, C, LC);
        k5_std<<<1, 64, 0, stream>>>(qstats, out, out_size - 1);
    }
}

// Round 11
// 199.811 us; speedup vs baseline: 1.0277x; 1.0277x over previous
//
#include <hip/hip_runtime.h>
#include <math.h>
#include <stdint.h>

#define B_ 16
#define L_ 512
#define IN_ 64
#define D_ 64
#define LP_ 8

#define LN_EPS 1e-5f
#define EPSF 1e-8f

__device__ __forceinline__ float wredf(float v){
    #pragma unroll
    for (int o = 32; o; o >>= 1) v += __shfl_xor(v, o, 64);
    return v;
}
__device__ __forceinline__ double wredd(double v){
    #pragma unroll
    for (int o = 32; o; o >>= 1) v += __shfl_xor(v, o, 64);
    return v;
}

// async global->LDS (fallback k4 only)
__device__ __forceinline__ void gl_lds4(const float* gsrc, float* ldst){
    __builtin_amdgcn_global_load_lds((const __attribute__((address_space(1))) void*)gsrc,
                                     (__attribute__((address_space(3))) void*)ldst, 4, 0, 0);
}

// ================= merged K0+K1: projections + chunk partials + prompt =================
// blocks 0..511: projection path (16 rows each, 4 rows/wave, weights read once per 4 rows)
// blocks 512..543: prompt path (old k1)
template<int LC, int NCH>
__global__ __launch_bounds__(256) void k0k1(
    const float* __restrict__ X,
    const float* __restrict__ Wq, const float* __restrict__ bq,
    const float* __restrict__ Wk, const float* __restrict__ bk,
    const float* __restrict__ Wv, const float* __restrict__ bv,
    float* __restrict__ Q, float* __restrict__ Z, float* __restrict__ V,
    float* __restrict__ spart, float* __restrict__ zpart,
    double* __restrict__ qstats, unsigned int* __restrict__ cnt,
    const float* __restrict__ Pm, const float* __restrict__ Sm,
    const float* __restrict__ z_g, const float* __restrict__ z_b,
    const float* __restrict__ s_g, const float* __restrict__ s_b,
    const float* __restrict__ nam_g, const float* __restrict__ nam_b,
    const int* __restrict__ user_id,
    const float* __restrict__ prev_z_buf, const float* __restrict__ prev_s_buf,
    float* __restrict__ Pz, float* __restrict__ Ps, float* __restrict__ prevLN)
{
    __shared__ float sW[3][IN_*D_];     // 48 KB
    __shared__ float sx[16][IN_];       // 4 KB
    __shared__ float sz[16][D_], sv[16][D_]; // 8 KB
    __shared__ double l2d[4][2];
    __shared__ float sca[1];
    int bid = blockIdx.x;
    int t = threadIdx.x, p = t & 63, g = t >> 6;

    if (bid >= 512){
        // ---------------- prompt path (old k1) ----------------
        int blk = bid - 512; int b = blk & (B_-1); int path = blk >> 4;
        const float* Xs = (path ? Sm : Pm) + (size_t)b*LP_*IN_;
        for (int idx = t; idx < 2*LP_*D_; idx += 256){
            int which = idx >> 9;
            int j = (idx >> 6) & 7;
            int d = idx & 63;
            const float* W = which ? Wv : Wk;
            float acc = which ? bv[d] : bk[d];
            const float* xr = Xs + j*IN_;
            #pragma unroll
            for (int i = 0; i < IN_; i++) acc = fmaf(xr[i], W[i*D_+d], acc);
            if (!which) acc = acc > 0.f ? acc : (expf(acc)-1.f);
            if (which) sv[j][d] = acc; else sz[j][d] = acc;
        }
        __syncthreads();
        if (t < 64){
            float zc = 0.f;
            #pragma unroll
            for (int j = 0; j < LP_; j++) zc += sz[j][t];
            double s1 = wredd((double)zc), s2 = wredd((double)zc*(double)zc);
            float mz = (float)(s1*(1.0/64));
            float vz = (float)(s2*(1.0/64) - (s1*(1.0/64))*(s1*(1.0/64)));
            float zf = fmaf((zc-mz)*rsqrtf(vz+LN_EPS), z_g[t], z_b[t]);
            if (path == 0){ Pz[b*D_+t] = zf; }
            else {
                int uid = user_id[b];
                float pz = prev_z_buf[(size_t)uid*D_+t] + zf;
                float rr = wredf(pz*pz);
                if (t == 0) sca[0] = fmaxf(sqrtf(rr), 1e-8f) + EPSF;
            }
        }
        float sc[16];
        #pragma unroll
        for (int i = 0; i < 16; i++){
            int d = g*16 + i; float a = 0.f;
            #pragma unroll
            for (int j = 0; j < LP_; j++) a = fmaf(sz[j][d], sv[j][p], a);
            sc[i] = a;
        }
        double m0 = 0, m1 = 0;
        #pragma unroll
        for (int i = 0; i < 16; i++){ double a = sc[i]; m0 += a; m1 += a*a; }
        m0 = wredd(m0); m1 = wredd(m1);
        __syncthreads();
        if (p == 0){ l2d[g][0] = m0; l2d[g][1] = m1; }
        __syncthreads();
        m0 = l2d[0][0]+l2d[1][0]+l2d[2][0]+l2d[3][0];
        m1 = l2d[0][1]+l2d[1][1]+l2d[2][1]+l2d[3][1];
        double mean1 = m0*(1.0/4096.0);
        double var1 = m1*(1.0/4096.0) - mean1*mean1;
        float inv1 = rsqrtf((float)var1 + LN_EPS);
        float mean1f = (float)mean1;
        float sl[16];
        #pragma unroll
        for (int i = 0; i < 16; i++){
            int e = (g*16+i)*D_ + p;
            sl[i] = fmaf((sc[i]-mean1f)*inv1, s_g[e], s_b[e]);
        }
        if (path == 0){
            #pragma unroll
            for (int i = 0; i < 16; i++) Ps[(size_t)b*4096 + (g*16+i)*D_ + p] = sl[i];
            return;
        }
        int uid = user_id[b];
        float denom = sca[0];
        float pn[16]; double n0 = 0, n1 = 0;
        #pragma unroll
        for (int i = 0; i < 16; i++){
            int e = (g*16+i)*D_ + p;
            float ps = prev_s_buf[(size_t)uid*4096 + e] + sl[i];
            float v = ps / denom;
            pn[i] = v; n0 += v; n1 += (double)v*(double)v;
        }
        n0 = wredd(n0); n1 = wredd(n1);
        __syncthreads();
        if (p == 0){ l2d[g][0] = n0; l2d[g][1] = n1; }
        __syncthreads();
        n0 = l2d[0][0]+l2d[1][0]+l2d[2][0]+l2d[3][0];
        n1 = l2d[0][1]+l2d[1][1]+l2d[2][1]+l2d[3][1];
        double meanp = n0*(1.0/4096.0);
        double varp = n1*(1.0/4096.0) - meanp*meanp;
        float invp = rsqrtf((float)varp + LN_EPS);
        float meanpf = (float)meanp;
        #pragma unroll
        for (int i = 0; i < 16; i++){
            int e = (g*16+i)*D_ + p;
            prevLN[(size_t)b*4096 + e] = fmaf((pn[i]-meanpf)*invp, nam_g[e], nam_b[e]);
        }
        return;
    }

    // ---------------- projection path ----------------
    if (bid == 0){
        if (t < 2) qstats[t] = 0.0;
        if (t == 2) *cnt = 0u;
    }
    int r0 = bid * 16;
    // stage weights (coalesced) and 16 X rows
    for (int k = t; k < IN_*D_; k += 256){ sW[0][k]=Wq[k]; sW[1][k]=Wk[k]; sW[2][k]=Wv[k]; }
    for (int k = t; k < 16*IN_; k += 256) sx[k>>6][k&63] = X[(size_t)(r0 + (k>>6))*IN_ + (k&63)];
    __syncthreads();
    float aq[4], ak[4], av[4];
    float bqv = bq[p], bkv = bk[p], bvv = bv[p];
    #pragma unroll
    for (int r = 0; r < 4; r++){ aq[r]=bqv; ak[r]=bkv; av[r]=bvv; }
    #pragma unroll
    for (int i = 0; i < IN_; i++){
        float wqv = sW[0][i*D_+p], wkv = sW[1][i*D_+p], wvv = sW[2][i*D_+p];
        #pragma unroll
        for (int r = 0; r < 4; r++){
            float x = sx[g*4+r][i];
            aq[r] = fmaf(x, wqv, aq[r]);
            ak[r] = fmaf(x, wkv, ak[r]);
            av[r] = fmaf(x, wvv, av[r]);
        }
    }
    #pragma unroll
    for (int r = 0; r < 4; r++){
        int lrow = g*4 + r;
        size_t row = r0 + lrow;
        float q = aq[r] > 0.f ? aq[r] : (expf(aq[r])-1.f);
        float z = ak[r] > 0.f ? ak[r] : (expf(ak[r])-1.f);
        Q[row*D_+p] = q; Z[row*D_+p] = z; V[row*D_+p] = av[r];
        sz[lrow][p] = z; sv[lrow][p] = av[r];
    }
    __syncthreads();
    int b = r0 >> 9;
    int c0 = (r0 & 511) / LC;
    #pragma unroll
    for (int ch = 0; ch < NCH; ch++){
        float acc[16];
        #pragma unroll
        for (int i = 0; i < 16; i++) acc[i] = 0.f;
        #pragma unroll
        for (int l = 0; l < LC; l++){
            float vv = sv[ch*LC+l][p];
            #pragma unroll
            for (int i = 0; i < 16; i++) acc[i] = fmaf(sz[ch*LC+l][g*16+i], vv, acc[i]);
        }
        size_t cg = (size_t)(b*(512/LC) + c0 + ch);
        size_t base = cg << 12;
        #pragma unroll
        for (int i = 0; i < 16; i++) spart[base + (g*16+i)*64 + p] = acc[i];
        if (g == 0){
            float za = 0.f;
            #pragma unroll
            for (int l = 0; l < LC; l++) za += sz[ch*LC+l][p];
            zpart[cg*64 + p] = za;
        }
    }
}

// ================= K3: register-array exclusive scan over chunks =================
template<int C>
__global__ __launch_bounds__(256) void k3_scan(
    float* __restrict__ spart, float* __restrict__ zpart)
{
    int id = blockIdx.x*256 + threadIdx.x;
    const int NS = B_*4096;
    if (id < NS){
        int b = id >> 12, e = id & 4095;
        float a[C];
        #pragma unroll
        for (int c = 0; c < C; c++) a[c] = spart[(((size_t)(b*C+c)) << 12) + e];
        float run = 0.f;
        #pragma unroll
        for (int c = 0; c < C; c++){ float tv = a[c]; a[c] = run; run += tv; }
        #pragma unroll
        for (int c = 0; c < C; c++) spart[(((size_t)(b*C+c)) << 12) + e] = a[c];
    } else if (id < NS + B_*64){
        int k = id - NS;
        int b = k >> 6, d = k & 63;
        float a[C];
        #pragma unroll
        for (int c = 0; c < C; c++) a[c] = zpart[(size_t)(b*C+c)*64 + d];
        float run = 0.f;
        #pragma unroll
        for (int c = 0; c < C; c++){ float tv = a[c]; a[c] = run; run += tv; }
        #pragma unroll
        for (int c = 0; c < C; c++) zpart[(size_t)(b*C+c)*64 + d] = a[c];
    }
}

// ================= K4 fused: parallel prologue + light scan loop + epilogue + std =================
// NOTE: plain __launch_bounds__(256) — the (256,4) variant capped VGPRs at 64 and
// spilled the 80-float per-thread state to scratch (+33 MB HBM traffic, 88 µs).
__global__ __launch_bounds__(256) void k4_fused(
    const float* __restrict__ Q, const float* __restrict__ Z, const float* __restrict__ V,
    const float* __restrict__ spart, const float* __restrict__ zpart,
    const float* __restrict__ Pz, const float* __restrict__ Ps,
    const float* __restrict__ prevLN,
    const float* __restrict__ z_g, const float* __restrict__ z_b,
    const float* __restrict__ s_g, const float* __restrict__ s_b,
    const float* __restrict__ nam_g, const float* __restrict__ nam_b,
    const float* __restrict__ na_g, const float* __restrict__ na_b,
    float* __restrict__ out, double* __restrict__ qstats,
    unsigned int* __restrict__ cnt, int outIdx)
{
    const int C_ = 64, LC = 8;
    int wg = blockIdx.x; int b = wg >> 6, c = wg & 63;
    int t = threadIdx.x, g = t >> 6, p = t & 63;
    __shared__ float lzall[LC][64], lvall[LC][64], lqall[LC][64]; // staged rows
    __shared__ float lnqall[LC][64];     // normalized q per step
    __shared__ float lnaAll[LC][4][64];  // per-wave na partials (deferred out-LN)
    __shared__ float lmd[2][4][6];
    __shared__ float lcs[4][5];
    __shared__ float lrA[LC];
    __shared__ double qpart[4][2];
    float A[16], Gv[16], Bv[16], NGv[16], NBv[16];
    size_t sbase = ((size_t)wg) << 12;
    size_t bbase = ((size_t)b) << 12;
    size_t row0 = (size_t)b*L_ + (size_t)c*LC;

    // stage all LC rows of Z,V,Q
    for (int k = t; k < 3*LC*64; k += 256){
        int arr = k / (LC*64);
        int idx = k - arr*(LC*64);
        int row = idx >> 6, col = idx & 63;
        float v = (arr==0 ? Z : (arr==1 ? V : Q))[(row0+row)*64 + col];
        if (arr == 0) lzall[row][col] = v;
        else if (arr == 1) lvall[row][col] = v;
        else lqall[row][col] = v;
    }
    #pragma unroll
    for (int i = 0; i < 16; i++){
        int e = (g*16+i)*64 + p;
        A[i]   = spart[sbase + e];
        Gv[i]  = s_g[e];
        Bv[i]  = s_b[e] + Ps[bbase + e];
        NGv[i] = nam_g[e];
        NBv[i] = nam_b[e] + prevLN[bbase + e];
    }
    float zcum = zpart[(size_t)wg*64 + p];
    float zgr = z_g[p], zbr = z_b[p], Pzv = Pz[b*64 + p];
    __syncthreads();   // staging visible

    // ---- parallel prologue: wave g owns steps 2g, 2g+1 ----
    {
        int l0 = 2*g;
        float zc = zcum;
        for (int j = 0; j <= l0; j++) zc += lzall[j][p];
        double qs = 0.0, qs2 = 0.0;
        #pragma unroll
        for (int s = 0; s < 2; s++){
            int l = l0 + s;
            if (s == 1) zc += lzall[l][p];
            float s1 = wredf(zc), s2 = wredf(zc*zc);
            float mz = s1*(1.f/64.f);
            float vz = s2*(1.f/64.f) - mz*mz;
            float zf = fmaf((zc-mz)*rsqrtf(vz+LN_EPS), zgr, zbr) + Pzv;
            float rr = wredf(zf*zf);
            if (p == 0) lrA[l] = fmaxf(sqrtf(rr), 1e-8f);
            float qv = lqall[l][p];
            float qq = wredf(qv*qv);
            lnqall[l][p] = qv / fmaxf(sqrtf(qq), 1e-8f);
            float qn = qv / fmaxf(zf, 1e-6f);
            qs += (double)qn; qs2 += (double)qn*(double)qn;
        }
        qs = wredd(qs); qs2 = wredd(qs2);
        if (p == 0){ qpart[g][0] = qs; qpart[g][1] = qs2; }
    }
    // block constants over the (G, B) tile
    {
        float cs0=0,cs1=0,cs2=0,cs3=0,cs4=0;
        #pragma unroll
        for (int i = 0; i < 16; i++){
            float gd = Gv[i], bd = Bv[i];
            cs0 += gd; cs1 += gd*gd; cs2 += bd; cs3 += bd*bd; cs4 += gd*bd;
        }
        cs0=wredf(cs0); cs1=wredf(cs1); cs2=wredf(cs2); cs3=wredf(cs3); cs4=wredf(cs4);
        if (p == 0){ lcs[g][0]=cs0; lcs[g][1]=cs1; lcs[g][2]=cs2; lcs[g][3]=cs3; lcs[g][4]=cs4; }
    }
    __syncthreads();   // lcs/lrA/lnqall visible
    float Cg  = lcs[0][0]+lcs[1][0]+lcs[2][0]+lcs[3][0];
    float Cg2 = lcs[0][1]+lcs[1][1]+lcs[2][1]+lcs[3][1];
    float Cb  = lcs[0][2]+lcs[1][2]+lcs[2][2]+lcs[3][2];
    float Cb2 = lcs[0][3]+lcs[1][3]+lcs[2][3]+lcs[3][3];
    float Cgb = lcs[0][4]+lcs[1][4]+lcs[2][4]+lcs[3][4];

    const float INV = 1.f/4096.f;
    // ---- main scan loop: 1 barrier/step, no serial chains except the 6-moment reduce ----
    for (int l = 0; l < LC; ++l){
        int cur = l & 1;
        float m0=0,m1=0,m2=0,m3=0,m4=0,m5=0;
        float vp = lvall[l][p];
        #pragma unroll
        for (int i = 0; i < 16; i++){
            A[i] = fmaf(lzall[l][g*16+i], vp, A[i]);
            float a = A[i];
            m0 += a; m1 = fmaf(a, a, m1);
            float tt = a * Gv[i];
            m2 += tt; m5 = fmaf(tt, tt, m5); m3 = fmaf(tt, Gv[i], m3); m4 = fmaf(tt, Bv[i], m4);
        }
        m0=wredf(m0); m1=wredf(m1); m2=wredf(m2); m3=wredf(m3); m4=wredf(m4); m5=wredf(m5);
        if (p == 0){
            lmd[cur][g][0]=m0; lmd[cur][g][1]=m1; lmd[cur][g][2]=m2;
            lmd[cur][g][3]=m3; lmd[cur][g][4]=m4; lmd[cur][g][5]=m5;
        }
        __syncthreads();
        float M0 = lmd[cur][0][0]+lmd[cur][1][0]+lmd[cur][2][0]+lmd[cur][3][0];
        float M1 = lmd[cur][0][1]+lmd[cur][1][1]+lmd[cur][2][1]+lmd[cur][3][1];
        float M2 = lmd[cur][0][2]+lmd[cur][1][2]+lmd[cur][2][2]+lmd[cur][3][2];
        float M3 = lmd[cur][0][3]+lmd[cur][1][3]+lmd[cur][2][3]+lmd[cur][3][3];
        float M4 = lmd[cur][0][4]+lmd[cur][1][4]+lmd[cur][2][4]+lmd[cur][3][4];
        float M5 = lmd[cur][0][5]+lmd[cur][1][5]+lmd[cur][2][5]+lmd[cur][3][5];
        float meanA = M0*INV;
        float varA  = M1*INV - meanA*meanA;
        float inv1 = rsqrtf(varA + LN_EPS);
        float sum_sf = inv1*(M2 - meanA*Cg) + Cb;
        float ssq_sf = inv1*inv1*(M5 - 2.f*meanA*M3 + meanA*meanA*Cg2)
                     + 2.f*inv1*(M4 - meanA*Cgb) + Cb2;
        float invr = 1.f / lrA[l];
        float mean_sf = sum_sf*INV;
        float var_sf  = ssq_sf*INV - mean_sf*mean_sf;
        float mean_nam = mean_sf * invr;
        float var_nam  = var_sf * invr * invr;
        float inv2 = rsqrtf(var_nam + LN_EPS);
        float nal = 0.f;
        #pragma unroll
        for (int i = 0; i < 16; i++){
            float sf = fmaf((A[i]-meanA)*inv1, Gv[i], Bv[i]);
            float nm = sf*invr;
            float elem = fmaf((nm-mean_nam)*inv2, NGv[i], NBv[i]);
            nal = fmaf(lnqall[l][g*16+i], elem, nal);
        }
        lnaAll[l][g][p] = nal;
    }
    __syncthreads();   // lnaAll complete

    // ---- epilogue: out-LN parallel across waves (2 rows each) ----
    {
        float nagr = na_g[p], nabr = na_b[p];
        #pragma unroll
        for (int s = 0; s < 2; s++){
            int l = 2*g + s;
            float nt = lnaAll[l][0][p]+lnaAll[l][1][p]+lnaAll[l][2][p]+lnaAll[l][3][p];
            float s1 = wredf(nt), s2 = wredf(nt*nt);
            float mu = s1*(1.f/64.f);
            float va = s2*(1.f/64.f) - mu*mu;
            out[(row0+l)*64 + p] = fmaf((nt-mu)*rsqrtf(va+LN_EPS), nagr, nabr);
        }
    }
    // ---- std: per-block atomics + completion counter (replaces k5) ----
    if (t == 0){
        double S  = qpart[0][0]+qpart[1][0]+qpart[2][0]+qpart[3][0];
        double S2 = qpart[0][1]+qpart[1][1]+qpart[2][1]+qpart[3][1];
        atomicAdd(&qstats[0], S);
        atomicAdd(&qstats[1], S2);
        __threadfence();
        unsigned int old = atomicAdd(cnt, 1u);
        if (old == (unsigned int)(B_*C_ - 1)){
            __threadfence();
            double sD  = *((volatile double*)&qstats[0]);
            double sqD = *((volatile double*)&qstats[1]);
            const double N = (double)(B_*L_*D_);
            double var = (sqD - sD*sD/N) / (N - 1.0);
            out[outIdx] = (float)sqrt(var > 0.0 ? var : 0.0);
        }
    }
}

// ================= fallback path (small workspace): old kernels =================
__global__ __launch_bounds__(256) void k0_qzv(
    const float* __restrict__ X,
    const float* __restrict__ Wq, const float* __restrict__ bq,
    const float* __restrict__ Wk, const float* __restrict__ bk,
    const float* __restrict__ Wv, const float* __restrict__ bv,
    float* __restrict__ Q, float* __restrict__ Z, float* __restrict__ V,
    double* __restrict__ qstats)
{
    __shared__ float sW[3][IN_*D_];
    __shared__ float sx[4][IN_];
    int t = threadIdx.x;
    if (blockIdx.x == 0 && t < 2) qstats[t] = 0.0;
    for (int i = t; i < IN_*D_; i += 256){ sW[0][i]=Wq[i]; sW[1][i]=Wk[i]; sW[2][i]=Wv[i]; }
    int p = t & 63, lr = t >> 6;
    float bqv = bq[p], bkv = bk[p], bvv = bv[p];
    for (int it = 0; it < 4; ++it){
        int r0 = blockIdx.x*16 + it*4;
        __syncthreads();
        for (int i = t; i < 4*IN_; i += 256)
            sx[i>>6][i&63] = X[(size_t)(r0 + (i>>6))*IN_ + (i&63)];
        __syncthreads();
        size_t row = r0 + lr;
        float aq = bqv, ak = bkv, av = bvv;
        #pragma unroll
        for (int i = 0; i < IN_; i++){
            float x = sx[lr][i];
            aq = fmaf(x, sW[0][i*D_+p], aq);
            ak = fmaf(x, sW[1][i*D_+p], ak);
            av = fmaf(x, sW[2][i*D_+p], av);
        }
        Q[row*D_+p] = aq > 0.f ? aq : (expf(aq)-1.f);
        Z[row*D_+p] = ak > 0.f ? ak : (expf(ak)-1.f);
        V[row*D_+p] = av;
    }
}

__global__ __launch_bounds__(256) void k1_prompt(
    const float* __restrict__ Pm, const float* __restrict__ Sm,
    const float* __restrict__ Wk, const float* __restrict__ bk,
    const float* __restrict__ Wv, const float* __restrict__ bv,
    const float* __restrict__ z_g, const float* __restrict__ z_b,
    const float* __restrict__ s_g, const float* __restrict__ s_b,
    const float* __restrict__ nam_g, const float* __restrict__ nam_b,
    const int* __restrict__ user_id,
    const float* __restrict__ prev_z_buf, const float* __restrict__ prev_s_buf,
    float* __restrict__ Pz, float* __restrict__ Ps, float* __restrict__ prevLN)
{
    __shared__ float sz[LP_][D_], sv[LP_][D_];
    __shared__ double lds[4][2];
    __shared__ float sca[1];
    int blk = blockIdx.x; int b = blk & (B_-1); int path = blk >> 4;
    int t = threadIdx.x, g = t >> 6, p = t & 63;
    const float* Xs = (path ? Sm : Pm) + (size_t)b*LP_*IN_;
    for (int idx = t; idx < 2*LP_*D_; idx += 256){
        int which = idx >> 9;
        int j = (idx >> 6) & 7;
        int d = idx & 63;
        const float* W = which ? Wv : Wk;
        float acc = which ? bv[d] : bk[d];
        const float* xr = Xs + j*IN_;
        #pragma unroll
        for (int i = 0; i < IN_; i++) acc = fmaf(xr[i], W[i*D_+d], acc);
        if (!which) acc = acc > 0.f ? acc : (expf(acc)-1.f);
        if (which) sv[j][d] = acc; else sz[j][d] = acc;
    }
    __syncthreads();
    if (t < 64){
        float zc = 0.f;
        #pragma unroll
        for (int j = 0; j < LP_; j++) zc += sz[j][t];
        double s1 = wredd((double)zc), s2 = wredd((double)zc*(double)zc);
        float mz = (float)(s1*(1.0/64));
        float vz = (float)(s2*(1.0/64) - (s1*(1.0/64))*(s1*(1.0/64)));
        float zf = fmaf((zc-mz)*rsqrtf(vz+LN_EPS), z_g[t], z_b[t]);
        if (path == 0){ Pz[b*D_+t] = zf; }
        else {
            int uid = user_id[b];
            float pz = prev_z_buf[(size_t)uid*D_+t] + zf;
            float rr = wredf(pz*pz);
            if (t == 0) sca[0] = fmaxf(sqrtf(rr), 1e-8f) + EPSF;
        }
    }
    float sc[16];
    #pragma unroll
    for (int i = 0; i < 16; i++){
        int d = g*16 + i; float a = 0.f;
        #pragma unroll
        for (int j = 0; j < LP_; j++) a = fmaf(sz[j][d], sv[j][p], a);
        sc[i] = a;
    }
    double m0 = 0, m1 = 0;
    #pragma unroll
    for (int i = 0; i < 16; i++){ double a = sc[i]; m0 += a; m1 += a*a; }
    m0 = wredd(m0); m1 = wredd(m1);
    __syncthreads();
    if (p == 0){ lds[g][0] = m0; lds[g][1] = m1; }
    __syncthreads();
    m0 = lds[0][0]+lds[1][0]+lds[2][0]+lds[3][0];
    m1 = lds[0][1]+lds[1][1]+lds[2][1]+lds[3][1];
    double mean1 = m0*(1.0/4096.0);
    double var1 = m1*(1.0/4096.0) - mean1*mean1;
    float inv1 = rsqrtf((float)var1 + LN_EPS);
    float mean1f = (float)mean1;
    float sl[16];
    #pragma unroll
    for (int i = 0; i < 16; i++){
        int e = (g*16+i)*D_ + p;
        sl[i] = fmaf((sc[i]-mean1f)*inv1, s_g[e], s_b[e]);
    }
    if (path == 0){
        #pragma unroll
        for (int i = 0; i < 16; i++) Ps[(size_t)b*4096 + (g*16+i)*D_ + p] = sl[i];
        return;
    }
    int uid = user_id[b];
    float denom = sca[0];
    float pn[16]; double n0 = 0, n1 = 0;
    #pragma unroll
    for (int i = 0; i < 16; i++){
        int e = (g*16+i)*D_ + p;
        float ps = prev_s_buf[(size_t)uid*4096 + e] + sl[i];
        float v = ps / denom;
        pn[i] = v; n0 += v; n1 += (double)v*(double)v;
    }
    n0 = wredd(n0); n1 = wredd(n1);
    __syncthreads();
    if (p == 0){ lds[g][0] = n0; lds[g][1] = n1; }
    __syncthreads();
    n0 = lds[0][0]+lds[1][0]+lds[2][0]+lds[3][0];
    n1 = lds[0][1]+lds[1][1]+lds[2][1]+lds[3][1];
    double meanp = n0*(1.0/4096.0);
    double varp = n1*(1.0/4096.0) - meanp*meanp;
    float invp = rsqrtf((float)varp + LN_EPS);
    float meanpf = (float)meanp;
    #pragma unroll
    for (int i = 0; i < 16; i++){
        int e = (g*16+i)*D_ + p;
        prevLN[(size_t)b*4096 + e] = fmaf((pn[i]-meanpf)*invp, nam_g[e], nam_b[e]);
    }
}

__global__ __launch_bounds__(256) void k2_chunks(
    const float* __restrict__ Z, const float* __restrict__ V,
    float* __restrict__ spart, float* __restrict__ zpart, int C_, int LC_)
{
    int wg = blockIdx.x; int b = wg / C_, c = wg - b*C_;
    int t = threadIdx.x, g = t >> 6, p = t & 63;
    __shared__ float lz[64], lv[64];
    float acc[16];
    #pragma unroll
    for (int i = 0; i < 16; i++) acc[i] = 0.f;
    float zacc = 0.f;
    for (int l = 0; l < LC_; l++){
        size_t row = (size_t)b*L_ + c*LC_ + l;
        __syncthreads();
        if (t < 64) lz[t] = Z[row*64 + t];
        else if (t < 128) lv[t-64] = V[row*64 + (t-64)];
        __syncthreads();
        float v = lv[p];
        #pragma unroll
        for (int i = 0; i < 16; i++) acc[i] = fmaf(lz[g*16+i], v, acc[i]);
        if (t < 64) zacc += lz[t];
    }
    size_t base = ((size_t)wg) << 12;
    #pragma unroll
    for (int i = 0; i < 16; i++) spart[base + (g*16+i)*64 + p] = acc[i];
    if (t < 64) zpart[(size_t)wg*64 + t] = zacc;
}

__global__ __launch_bounds__(256) void k3_serial(
    float* __restrict__ spart, float* __restrict__ zpart, int C_)
{
    int id = blockIdx.x*256 + threadIdx.x;
    const int NS = B_*4096;
    if (id < NS){
        int b = id >> 12;
        int e = id & 4095;
        float run = 0.f;
        for (int c = 0; c < C_; ++c){
            float* ptr = spart + (((size_t)(b*C_+c)) << 12) + e;
            float tv = *ptr; *ptr = run; run += tv;
        }
    } else if (id < NS + B_*64){
        int k = id - NS;
        int b = k >> 6, d = k & 63;
        float run = 0.f;
        for (int c = 0; c < C_; ++c){
            float* ptr = zpart + (size_t)(b*C_+c)*64 + d;
            float tv = *ptr; *ptr = run; run += tv;
        }
    }
}

__global__ __launch_bounds__(256) void k4_main(
    const float* __restrict__ Q, const float* __restrict__ Z, const float* __restrict__ V,
    const float* __restrict__ spart, const float* __restrict__ zpart,
    const float* __restrict__ Pz, const float* __restrict__ Ps,
    const float* __restrict__ prevLN,
    const float* __restrict__ z_g, const float* __restrict__ z_b,
    const float* __restrict__ s_g, const float* __restrict__ s_b,
    const float* __restrict__ nam_g, const float* __restrict__ nam_b,
    const float* __restrict__ na_g, const float* __restrict__ na_b,
    float* __restrict__ out, double* qstats, int C_, int LC_)
{
    int wg = blockIdx.x; int b = wg / C_, c = wg - b*C_;
    int t = threadIdx.x, g = t >> 6, p = t & 63;
    __shared__ float lz[2][64], lv[2][64], lqb[2][64], lnq[2][64];
    __shared__ float lna[2][4][64];
    __shared__ float lmd[2][4][6];
    __shared__ float lcs[4][5];
    __shared__ float lr[2];
    __shared__ float lPz[64];
    float A[16], Gv[16], Bv[16], NGv[16], NBv[16];
    size_t sbase = ((size_t)wg) << 12;
    size_t bbase = ((size_t)b) << 12;
    size_t row0 = (size_t)b*L_ + (size_t)c*LC_;
    if (g == 1) gl_lds4(Q + row0*64 + p, &lqb[0][0]);
    else if (g == 2) gl_lds4(Z + row0*64 + p, &lz[0][0]);
    else if (g == 3) gl_lds4(V + row0*64 + p, &lv[0][0]);
    #pragma unroll
    for (int i = 0; i < 16; i++){
        int e = (g*16+i)*64 + p;
        A[i]   = spart[sbase + e];
        Gv[i]  = s_g[e];
        Bv[i]  = s_b[e] + Ps[bbase + e];
        NGv[i] = nam_g[e];
        NBv[i] = nam_b[e] + prevLN[bbase + e];
    }
    float cs0=0,cs1=0,cs2=0,cs3=0,cs4=0;
    #pragma unroll
    for (int i = 0; i < 16; i++){
        float gd = Gv[i], bd = Bv[i];
        cs0 += gd; cs1 += gd*gd; cs2 += bd; cs3 += bd*bd; cs4 += gd*bd;
    }
    cs0=wredf(cs0); cs1=wredf(cs1); cs2=wredf(cs2); cs3=wredf(cs3); cs4=wredf(cs4);
    if (p == 0){ lcs[g][0]=cs0; lcs[g][1]=cs1; lcs[g][2]=cs2; lcs[g][3]=cs3; lcs[g][4]=cs4; }
    float zc=0.f, zgr=0.f, zbr=0.f, nagr=0.f, nabr=0.f;
    if (g == 0){
        zc = zpart[(size_t)wg*64 + p];
        lPz[p] = Pz[b*64 + p];
        zgr = z_g[p]; zbr = z_b[p];
    }
    if (g == 3){ nagr = na_g[p]; nabr = na_b[p]; }
    __syncthreads();
    float Cg  = lcs[0][0]+lcs[1][0]+lcs[2][0]+lcs[3][0];
    float Cg2 = lcs[0][1]+lcs[1][1]+lcs[2][1]+lcs[3][1];
    float Cb  = lcs[0][2]+lcs[1][2]+lcs[2][2]+lcs[3][2];
    float Cb2 = lcs[0][3]+lcs[1][3]+lcs[2][3]+lcs[3][3];
    float Cgb = lcs[0][4]+lcs[1][4]+lcs[2][4]+lcs[3][4];

    double qsum = 0.0, qsq = 0.0;
    const float INV = 1.f/4096.f;
    for (int ll = 0; ll < LC_; ++ll){
        int cur = ll & 1, nxt = cur ^ 1, prv = cur ^ 1;
        size_t row = row0 + ll;
        if (ll + 1 < LC_){
            if (g == 1) gl_lds4(Q + (row+1)*64 + p, &lqb[nxt][0]);
            else if (g == 2) gl_lds4(Z + (row+1)*64 + p, &lz[nxt][0]);
            else if (g == 3) gl_lds4(V + (row+1)*64 + p, &lv[nxt][0]);
        }
        if (g == 0){
            float zl = lz[cur][p]; zc += zl;
            float s1 = wredf(zc), s2 = wredf(zc*zc);
            float mz = s1*(1.f/64.f);
            float vz = s2*(1.f/64.f) - mz*mz;
            float zf = fmaf((zc-mz)*rsqrtf(vz+LN_EPS), zgr, zbr) + lPz[p];
            float rr = wredf(zf*zf);
            if (p == 0) lr[cur] = fmaxf(sqrtf(rr), 1e-8f);
            float qvv = lqb[cur][p];
            float qn = qvv / fmaxf(zf, 1e-6f);
            qsum += (double)qn; qsq += (double)qn*(double)qn;
        }
        if (g == 1){
            float qvv = lqb[cur][p];
            float qq = wredf(qvv*qvv);
            lnq[cur][p] = qvv / fmaxf(sqrtf(qq), 1e-8f);
        }
        float m0=0,m1=0,m2=0,m3=0,m4=0,m5=0;
        float vp = lv[cur][p];
        #pragma unroll
        for (int i = 0; i < 16; i++){
            A[i] = fmaf(lz[cur][g*16+i], vp, A[i]);
            float a = A[i];
            m0 += a; m1 = fmaf(a, a, m1);
            float tt = a * Gv[i];
            m2 += tt; m5 = fmaf(tt, tt, m5); m3 = fmaf(tt, Gv[i], m3); m4 = fmaf(tt, Bv[i], m4);
        }
        m0=wredf(m0); m1=wredf(m1); m2=wredf(m2); m3=wredf(m3); m4=wredf(m4); m5=wredf(m5);
        if (p == 0){
            lmd[cur][g][0]=m0; lmd[cur][g][1]=m1; lmd[cur][g][2]=m2;
            lmd[cur][g][3]=m3; lmd[cur][g][4]=m4; lmd[cur][g][5]=m5;
        }
        __syncthreads();
        float M0 = lmd[cur][0][0]+lmd[cur][1][0]+lmd[cur][2][0]+lmd[cur][3][0];
        float M1 = lmd[cur][0][1]+lmd[cur][1][1]+lmd[cur][2][1]+lmd[cur][3][1];
        float M2 = lmd[cur][0][2]+lmd[cur][1][2]+lmd[cur][2][2]+lmd[cur][3][2];
        float M3 = lmd[cur][0][3]+lmd[cur][1][3]+lmd[cur][2][3]+lmd[cur][3][3];
        float M4 = lmd[cur][0][4]+lmd[cur][1][4]+lmd[cur][2][4]+lmd[cur][3][4];
        float M5 = lmd[cur][0][5]+lmd[cur][1][5]+lmd[cur][2][5]+lmd[cur][3][5];
        float meanA = M0*INV;
        float varA  = M1*INV - meanA*meanA;
        float inv1 = rsqrtf(varA + LN_EPS);
        float sum_sf = inv1*(M2 - meanA*Cg) + Cb;
        float ssq_sf = inv1*inv1*(M5 - 2.f*meanA*M3 + meanA*meanA*Cg2)
                     + 2.f*inv1*(M4 - meanA*Cgb) + Cb2;
        float r = lr[cur];
        float invr = 1.f/r;
        float mean_sf = sum_sf*INV;
        float var_sf  = ssq_sf*INV - mean_sf*mean_sf;
        float mean_nam = mean_sf * invr;
        float var_nam  = var_sf * invr * invr;
        float inv2 = rsqrtf(var_nam + LN_EPS);
        float nal = 0.f;
        #pragma unroll
        for (int i = 0; i < 16; i++){
            float sf = fmaf((A[i]-meanA)*inv1, Gv[i], Bv[i]);
            float nm = sf*invr;
            float elem = fmaf((nm-mean_nam)*inv2, NGv[i], NBv[i]);
            nal = fmaf(lnq[cur][g*16+i], elem, nal);
        }
        lna[cur][g][p] = nal;
        if (g == 3 && ll > 0){
            float nt = lna[prv][0][p]+lna[prv][1][p]+lna[prv][2][p]+lna[prv][3][p];
            float s1 = wredf(nt), s2 = wredf(nt*nt);
            float mu = s1*(1.f/64.f);
            float va = s2*(1.f/64.f) - mu*mu;
            out[(row-1)*64 + p] = fmaf((nt-mu)*rsqrtf(va+LN_EPS), nagr, nabr);
        }
    }
    __syncthreads();
    if (g == 3){
        int lastc = (LC_-1) & 1;
        float nt = lna[lastc][0][p]+lna[lastc][1][p]+lna[lastc][2][p]+lna[lastc][3][p];
        float s1 = wredf(nt), s2 = wredf(nt*nt);
        float mu = s1*(1.f/64.f);
        float va = s2*(1.f/64.f) - mu*mu;
        out[(row0+LC_-1)*64 + p] = fmaf((nt-mu)*rsqrtf(va+LN_EPS), nagr, nabr);
    }
    if (g == 0){
        double s = wredd(qsum), s2 = wredd(qsq);
        if (p == 0){
            atomicAdd(&qstats[0], s);
            atomicAdd(&qstats[1], s2);
        }
    }
}

__global__ void k5_std(const double* __restrict__ qstats, float* __restrict__ out, int idx){
    if (threadIdx.x == 0 && blockIdx.x == 0){
        double s = qstats[0], sq = qstats[1];
        const double N = (double)(B_*L_*D_);
        double var = (sq - s*s/N) / (N - 1.0);
        out[idx] = (float)sqrt(var > 0.0 ? var : 0.0);
    }
}

extern "C" void kernel_launch(void* const* d_in, const int* in_sizes, int n_in,
                              void* d_out, int out_size, void* d_ws, size_t ws_size,
                              hipStream_t stream)
{
    (void)in_sizes; (void)n_in;
    const int*   user_id    = (const int*)d_in[0];
    const float* seqs       = (const float*)d_in[1];
    const float* Pm         = (const float*)d_in[2];
    const float* Sm         = (const float*)d_in[3];
    const float* Wq         = (const float*)d_in[4];
    const float* bq         = (const float*)d_in[5];
    const float* Wk         = (const float*)d_in[6];
    const float* bk         = (const float*)d_in[7];
    const float* Wv         = (const float*)d_in[8];
    const float* bv         = (const float*)d_in[9];
    const float* z_g        = (const float*)d_in[10];
    const float* z_b        = (const float*)d_in[11];
    const float* s_g        = (const float*)d_in[12];
    const float* s_b        = (const float*)d_in[13];
    const float* nam_g      = (const float*)d_in[14];
    const float* nam_b      = (const float*)d_in[15];
    const float* na_g       = (const float*)d_in[16];
    const float* na_b       = (const float*)d_in[17];
    const float* prev_z_buf = (const float*)d_in[18];
    const float* prev_s_buf = (const float*)d_in[19];
    float* out = (float*)d_out;

    char* w = (char*)d_ws;
    double* qstats = (double*)w;                     // 16 B
    unsigned int* cnt = (unsigned int*)(w + 16);     // 4 B (pad to 32)
    float* Q  = (float*)(w + 32);                    // 524288
    float* Zb = Q  + 524288;
    float* Vb = Zb + 524288;
    float* Pz = Vb + 524288;                         // 1024
    float* Ps = Pz + 1024;                           // 65536
    float* prevLN = Ps + 65536;                      // 65536
    float* spart  = prevLN + 65536;                  // 16*C*4096
    size_t fixedBytes = 32 + (size_t)(3*524288 + 1024 + 2*65536)*4;
    int C = 64;
    while (C > 1 && fixedBytes + (size_t)16*C*(4096+64)*4 > ws_size) C >>= 1;
    int LC = 512 / C;
    float* zpart = spart + (size_t)16*C*4096;

    if (C == 64){
        k0k1<8,2><<<544, 256, 0, stream>>>(seqs, Wq, bq, Wk, bk, Wv, bv,
                                           Q, Zb, Vb, spart, zpart, qstats, cnt,
                                           Pm, Sm, z_g, z_b, s_g, s_b, nam_g, nam_b,
                                           user_id, prev_z_buf, prev_s_buf,
                                           Pz, Ps, prevLN);
        k3_scan<64><<<(16*4096 + 16*64 + 255)/256, 256, 0, stream>>>(spart, zpart);
        k4_fused<<<16*64, 256, 0, stream>>>(Q, Zb, Vb, spart, zpart, Pz, Ps, prevLN,
                                            z_g, z_b, s_g, s_b, nam_g, nam_b, na_g, na_b,
                                            out, qstats, cnt, out_size - 1);
    } else {
        k0_qzv<<<512, 256, 0, stream>>>(seqs, Wq, bq, Wk, bk, Wv, bv, Q, Zb, Vb, qstats);
        k1_prompt<<<32, 256, 0, stream>>>(Pm, Sm, Wk, bk, Wv, bv, z_g, z_b, s_g, s_b,
                                          nam_g, nam_b, user_id, prev_z_buf, prev_s_buf,
                                          Pz, Ps, prevLN);
        k2_chunks<<<16*C, 256, 0, stream>>>(Zb, Vb, spart, zpart, C, LC);
        k3_serial<<<(16*4096 + 16*64 + 255)/256, 256, 0, stream>>>(spart, zpart, C);
        k4_main<<<16*C, 256, 0, stream>>>(Q, Zb, Vb, spart, zpart, Pz, Ps, prevLN,
                                          z_g, z_b, s_g, s_b, nam_g, nam_b, na_g, na_b,
                                          out, qstats, C, LC);
        k5_std<<<1, 64, 0, stream>>>(qstats, out, out_size - 1);
    }
}

// Round 12
// 190.338 us; speedup vs baseline: 1.0788x; 1.0498x over previous
//
#include <hip/hip_runtime.h>
#include <math.h>
#include <stdint.h>

#define B_ 16
#define L_ 512
#define IN_ 64
#define D_ 64
#define LP_ 8

#define LN_EPS 1e-5f
#define EPSF 1e-8f

// f32 wave-reduce via DPP butterfly (VALU-speed, ~40cy) instead of __shfl_xor
// (ds_bpermute, ~120cy/level x 6 dependent levels). xor4/xor8 use half_mirror/
// mirror which are valid pair-swaps once 4-groups hold equal values.
__device__ __forceinline__ float wredf(float v){
    int x = __float_as_int(v);
    v += __int_as_float(__builtin_amdgcn_update_dpp(0, x, 0xB1, 0xF, 0xF, true));  // quad_perm [1,0,3,2] = xor1
    x = __float_as_int(v);
    v += __int_as_float(__builtin_amdgcn_update_dpp(0, x, 0x4E, 0xF, 0xF, true));  // quad_perm [2,3,0,1] = xor2
    x = __float_as_int(v);
    v += __int_as_float(__builtin_amdgcn_update_dpp(0, x, 0x141, 0xF, 0xF, true)); // row_half_mirror ~ xor4
    x = __float_as_int(v);
    v += __int_as_float(__builtin_amdgcn_update_dpp(0, x, 0x140, 0xF, 0xF, true)); // row_mirror ~ xor8
    int y = __float_as_int(v);
    return __int_as_float(__builtin_amdgcn_readlane(y, 0))
         + __int_as_float(__builtin_amdgcn_readlane(y, 16))
         + __int_as_float(__builtin_amdgcn_readlane(y, 32))
         + __int_as_float(__builtin_amdgcn_readlane(y, 48));
}
__device__ __forceinline__ double wredd(double v){
    #pragma unroll
    for (int o = 32; o; o >>= 1) v += __shfl_xor(v, o, 64);
    return v;
}

// async global->LDS (fallback k4 only)
__device__ __forceinline__ void gl_lds4(const float* gsrc, float* ldst){
    __builtin_amdgcn_global_load_lds((const __attribute__((address_space(1))) void*)gsrc,
                                     (__attribute__((address_space(3))) void*)ldst, 4, 0, 0);
}

// ================= merged K0+K1: projections + chunk partials + prompt =================
template<int LC, int NCH>
__global__ __launch_bounds__(256) void k0k1(
    const float* __restrict__ X,
    const float* __restrict__ Wq, const float* __restrict__ bq,
    const float* __restrict__ Wk, const float* __restrict__ bk,
    const float* __restrict__ Wv, const float* __restrict__ bv,
    float* __restrict__ Q, float* __restrict__ Z, float* __restrict__ V,
    float* __restrict__ spart, float* __restrict__ zpart,
    double* __restrict__ qstats, unsigned int* __restrict__ cnt,
    const float* __restrict__ Pm, const float* __restrict__ Sm,
    const float* __restrict__ z_g, const float* __restrict__ z_b,
    const float* __restrict__ s_g, const float* __restrict__ s_b,
    const float* __restrict__ nam_g, const float* __restrict__ nam_b,
    const int* __restrict__ user_id,
    const float* __restrict__ prev_z_buf, const float* __restrict__ prev_s_buf,
    float* __restrict__ Pz, float* __restrict__ Ps, float* __restrict__ prevLN)
{
    __shared__ float sW[3][IN_*D_];     // 48 KB
    __shared__ float sx[16][IN_];       // 4 KB
    __shared__ float sz[16][D_], sv[16][D_]; // 8 KB
    __shared__ double l2d[4][2];
    __shared__ float sca[1];
    int bid = blockIdx.x;
    int t = threadIdx.x, p = t & 63, g = t >> 6;

    if (bid >= 512){
        // ---------------- prompt path (old k1) ----------------
        int blk = bid - 512; int b = blk & (B_-1); int path = blk >> 4;
        const float* Xs = (path ? Sm : Pm) + (size_t)b*LP_*IN_;
        for (int idx = t; idx < 2*LP_*D_; idx += 256){
            int which = idx >> 9;
            int j = (idx >> 6) & 7;
            int d = idx & 63;
            const float* W = which ? Wv : Wk;
            float acc = which ? bv[d] : bk[d];
            const float* xr = Xs + j*IN_;
            #pragma unroll
            for (int i = 0; i < IN_; i++) acc = fmaf(xr[i], W[i*D_+d], acc);
            if (!which) acc = acc > 0.f ? acc : (expf(acc)-1.f);
            if (which) sv[j][d] = acc; else sz[j][d] = acc;
        }
        __syncthreads();
        if (t < 64){
            float zc = 0.f;
            #pragma unroll
            for (int j = 0; j < LP_; j++) zc += sz[j][t];
            double s1 = wredd((double)zc), s2 = wredd((double)zc*(double)zc);
            float mz = (float)(s1*(1.0/64));
            float vz = (float)(s2*(1.0/64) - (s1*(1.0/64))*(s1*(1.0/64)));
            float zf = fmaf((zc-mz)*rsqrtf(vz+LN_EPS), z_g[t], z_b[t]);
            if (path == 0){ Pz[b*D_+t] = zf; }
            else {
                int uid = user_id[b];
                float pz = prev_z_buf[(size_t)uid*D_+t] + zf;
                float rr = wredf(pz*pz);
                if (t == 0) sca[0] = fmaxf(sqrtf(rr), 1e-8f) + EPSF;
            }
        }
        float sc[16];
        #pragma unroll
        for (int i = 0; i < 16; i++){
            int d = g*16 + i; float a = 0.f;
            #pragma unroll
            for (int j = 0; j < LP_; j++) a = fmaf(sz[j][d], sv[j][p], a);
            sc[i] = a;
        }
        double m0 = 0, m1 = 0;
        #pragma unroll
        for (int i = 0; i < 16; i++){ double a = sc[i]; m0 += a; m1 += a*a; }
        m0 = wredd(m0); m1 = wredd(m1);
        __syncthreads();
        if (p == 0){ l2d[g][0] = m0; l2d[g][1] = m1; }
        __syncthreads();
        m0 = l2d[0][0]+l2d[1][0]+l2d[2][0]+l2d[3][0];
        m1 = l2d[0][1]+l2d[1][1]+l2d[2][1]+l2d[3][1];
        double mean1 = m0*(1.0/4096.0);
        double var1 = m1*(1.0/4096.0) - mean1*mean1;
        float inv1 = rsqrtf((float)var1 + LN_EPS);
        float mean1f = (float)mean1;
        float sl[16];
        #pragma unroll
        for (int i = 0; i < 16; i++){
            int e = (g*16+i)*D_ + p;
            sl[i] = fmaf((sc[i]-mean1f)*inv1, s_g[e], s_b[e]);
        }
        if (path == 0){
            #pragma unroll
            for (int i = 0; i < 16; i++) Ps[(size_t)b*4096 + (g*16+i)*D_ + p] = sl[i];
            return;
        }
        int uid = user_id[b];
        float denom = sca[0];
        float pn[16]; double n0 = 0, n1 = 0;
        #pragma unroll
        for (int i = 0; i < 16; i++){
            int e = (g*16+i)*D_ + p;
            float ps = prev_s_buf[(size_t)uid*4096 + e] + sl[i];
            float v = ps / denom;
            pn[i] = v; n0 += v; n1 += (double)v*(double)v;
        }
        n0 = wredd(n0); n1 = wredd(n1);
        __syncthreads();
        if (p == 0){ l2d[g][0] = n0; l2d[g][1] = n1; }
        __syncthreads();
        n0 = l2d[0][0]+l2d[1][0]+l2d[2][0]+l2d[3][0];
        n1 = l2d[0][1]+l2d[1][1]+l2d[2][1]+l2d[3][1];
        double meanp = n0*(1.0/4096.0);
        double varp = n1*(1.0/4096.0) - meanp*meanp;
        float invp = rsqrtf((float)varp + LN_EPS);
        float meanpf = (float)meanp;
        #pragma unroll
        for (int i = 0; i < 16; i++){
            int e = (g*16+i)*D_ + p;
            prevLN[(size_t)b*4096 + e] = fmaf((pn[i]-meanpf)*invp, nam_g[e], nam_b[e]);
        }
        return;
    }

    // ---------------- projection path ----------------
    if (bid == 0){
        if (t < 2) qstats[t] = 0.0;
        if (t == 2) *cnt = 0u;
    }
    int r0 = bid * 16;
    for (int k = t; k < IN_*D_; k += 256){ sW[0][k]=Wq[k]; sW[1][k]=Wk[k]; sW[2][k]=Wv[k]; }
    for (int k = t; k < 16*IN_; k += 256) sx[k>>6][k&63] = X[(size_t)(r0 + (k>>6))*IN_ + (k&63)];
    __syncthreads();
    float aq[4], ak[4], av[4];
    float bqv = bq[p], bkv = bk[p], bvv = bv[p];
    #pragma unroll
    for (int r = 0; r < 4; r++){ aq[r]=bqv; ak[r]=bkv; av[r]=bvv; }
    #pragma unroll
    for (int i = 0; i < IN_; i++){
        float wqv = sW[0][i*D_+p], wkv = sW[1][i*D_+p], wvv = sW[2][i*D_+p];
        #pragma unroll
        for (int r = 0; r < 4; r++){
            float x = sx[g*4+r][i];
            aq[r] = fmaf(x, wqv, aq[r]);
            ak[r] = fmaf(x, wkv, ak[r]);
            av[r] = fmaf(x, wvv, av[r]);
        }
    }
    #pragma unroll
    for (int r = 0; r < 4; r++){
        int lrow = g*4 + r;
        size_t row = r0 + lrow;
        float q = aq[r] > 0.f ? aq[r] : (expf(aq[r])-1.f);
        float z = ak[r] > 0.f ? ak[r] : (expf(ak[r])-1.f);
        Q[row*D_+p] = q; Z[row*D_+p] = z; V[row*D_+p] = av[r];
        sz[lrow][p] = z; sv[lrow][p] = av[r];
    }
    __syncthreads();
    int b = r0 >> 9;
    int c0 = (r0 & 511) / LC;
    #pragma unroll
    for (int ch = 0; ch < NCH; ch++){
        float acc[16];
        #pragma unroll
        for (int i = 0; i < 16; i++) acc[i] = 0.f;
        #pragma unroll
        for (int l = 0; l < LC; l++){
            float vv = sv[ch*LC+l][p];
            #pragma unroll
            for (int i = 0; i < 16; i++) acc[i] = fmaf(sz[ch*LC+l][g*16+i], vv, acc[i]);
        }
        size_t cg = (size_t)(b*(512/LC) + c0 + ch);
        size_t base = cg << 12;
        #pragma unroll
        for (int i = 0; i < 16; i++) spart[base + (g*16+i)*64 + p] = acc[i];
        if (g == 0){
            float za = 0.f;
            #pragma unroll
            for (int l = 0; l < LC; l++) za += sz[ch*LC+l][p];
            zpart[cg*64 + p] = za;
        }
    }
}

// ================= K3: register-array exclusive scan over chunks =================
template<int C>
__global__ __launch_bounds__(256) void k3_scan(
    float* __restrict__ spart, float* __restrict__ zpart)
{
    int id = blockIdx.x*256 + threadIdx.x;
    const int NS = B_*4096;
    if (id < NS){
        int b = id >> 12, e = id & 4095;
        float a[C];
        #pragma unroll
        for (int c = 0; c < C; c++) a[c] = spart[(((size_t)(b*C+c)) << 12) + e];
        float run = 0.f;
        #pragma unroll
        for (int c = 0; c < C; c++){ float tv = a[c]; a[c] = run; run += tv; }
        #pragma unroll
        for (int c = 0; c < C; c++) spart[(((size_t)(b*C+c)) << 12) + e] = a[c];
    } else if (id < NS + B_*64){
        int k = id - NS;
        int b = k >> 6, d = k & 63;
        float a[C];
        #pragma unroll
        for (int c = 0; c < C; c++) a[c] = zpart[(size_t)(b*C+c)*64 + d];
        float run = 0.f;
        #pragma unroll
        for (int c = 0; c < C; c++){ float tv = a[c]; a[c] = run; run += tv; }
        #pragma unroll
        for (int c = 0; c < C; c++) zpart[(size_t)(b*C+c)*64 + d] = a[c];
    }
}

// ================= K4 fused: parallel prologue + light scan loop + epilogue + std =================
__global__ __launch_bounds__(256) void k4_fused(
    const float* __restrict__ Q, const float* __restrict__ Z, const float* __restrict__ V,
    const float* __restrict__ spart, const float* __restrict__ zpart,
    const float* __restrict__ Pz, const float* __restrict__ Ps,
    const float* __restrict__ prevLN,
    const float* __restrict__ z_g, const float* __restrict__ z_b,
    const float* __restrict__ s_g, const float* __restrict__ s_b,
    const float* __restrict__ nam_g, const float* __restrict__ nam_b,
    const float* __restrict__ na_g, const float* __restrict__ na_b,
    float* __restrict__ out, double* __restrict__ qstats,
    unsigned int* __restrict__ cnt, int outIdx)
{
    const int C_ = 64, LC = 8;
    int wg = blockIdx.x; int b = wg >> 6, c = wg & 63;
    int t = threadIdx.x, g = t >> 6, p = t & 63;
    __shared__ float lzall[LC][64], lvall[LC][64], lqall[LC][64];
    __shared__ float lnqall[LC][64];
    __shared__ float lnaAll[LC][4][64];
    __shared__ float lmd[2][4][6];
    __shared__ float lcs[4][5];
    __shared__ float lrA[LC];
    __shared__ double qpart[4][2];
    float A[16], Gv[16], Bv[16], NGv[16], NBv[16];
    size_t sbase = ((size_t)wg) << 12;
    size_t bbase = ((size_t)b) << 12;
    size_t row0 = (size_t)b*L_ + (size_t)c*LC;

    for (int k = t; k < 3*LC*64; k += 256){
        int arr = k / (LC*64);
        int idx = k - arr*(LC*64);
        int row = idx >> 6, col = idx & 63;
        float v = (arr==0 ? Z : (arr==1 ? V : Q))[(row0+row)*64 + col];
        if (arr == 0) lzall[row][col] = v;
        else if (arr == 1) lvall[row][col] = v;
        else lqall[row][col] = v;
    }
    #pragma unroll
    for (int i = 0; i < 16; i++){
        int e = (g*16+i)*64 + p;
        A[i]   = spart[sbase + e];
        Gv[i]  = s_g[e];
        Bv[i]  = s_b[e] + Ps[bbase + e];
        NGv[i] = nam_g[e];
        NBv[i] = nam_b[e] + prevLN[bbase + e];
    }
    float zcum = zpart[(size_t)wg*64 + p];
    float zgr = z_g[p], zbr = z_b[p], Pzv = Pz[b*64 + p];
    __syncthreads();   // staging visible

    // ---- parallel prologue: wave g owns steps 2g, 2g+1 ----
    {
        int l0 = 2*g;
        float zc = zcum;
        for (int j = 0; j <= l0; j++) zc += lzall[j][p];
        double qs = 0.0, qs2 = 0.0;
        #pragma unroll
        for (int s = 0; s < 2; s++){
            int l = l0 + s;
            if (s == 1) zc += lzall[l][p];
            float s1 = wredf(zc), s2 = wredf(zc*zc);
            float mz = s1*(1.f/64.f);
            float vz = s2*(1.f/64.f) - mz*mz;
            float zf = fmaf((zc-mz)*rsqrtf(vz+LN_EPS), zgr, zbr) + Pzv;
            float rr = wredf(zf*zf);
            if (p == 0) lrA[l] = fmaxf(sqrtf(rr), 1e-8f);
            float qv = lqall[l][p];
            float qq = wredf(qv*qv);
            lnqall[l][p] = qv / fmaxf(sqrtf(qq), 1e-8f);
            float qn = qv / fmaxf(zf, 1e-6f);
            qs += (double)qn; qs2 += (double)qn*(double)qn;
        }
        qs = wredd(qs); qs2 = wredd(qs2);
        if (p == 0){ qpart[g][0] = qs; qpart[g][1] = qs2; }
    }
    // block constants over the (G, B) tile
    {
        float cs0=0,cs1=0,cs2=0,cs3=0,cs4=0;
        #pragma unroll
        for (int i = 0; i < 16; i++){
            float gd = Gv[i], bd = Bv[i];
            cs0 += gd; cs1 += gd*gd; cs2 += bd; cs3 += bd*bd; cs4 += gd*bd;
        }
        cs0=wredf(cs0); cs1=wredf(cs1); cs2=wredf(cs2); cs3=wredf(cs3); cs4=wredf(cs4);
        if (p == 0){ lcs[g][0]=cs0; lcs[g][1]=cs1; lcs[g][2]=cs2; lcs[g][3]=cs3; lcs[g][4]=cs4; }
    }
    __syncthreads();   // lcs/lrA/lnqall visible
    float Cg  = lcs[0][0]+lcs[1][0]+lcs[2][0]+lcs[3][0];
    float Cg2 = lcs[0][1]+lcs[1][1]+lcs[2][1]+lcs[3][1];
    float Cb  = lcs[0][2]+lcs[1][2]+lcs[2][2]+lcs[3][2];
    float Cb2 = lcs[0][3]+lcs[1][3]+lcs[2][3]+lcs[3][3];
    float Cgb = lcs[0][4]+lcs[1][4]+lcs[2][4]+lcs[3][4];

    const float INV = 1.f/4096.f;
    for (int l = 0; l < LC; ++l){
        int cur = l & 1;
        float m0=0,m1=0,m2=0,m3=0,m4=0,m5=0;
        float vp = lvall[l][p];
        #pragma unroll
        for (int i = 0; i < 16; i++){
            A[i] = fmaf(lzall[l][g*16+i], vp, A[i]);
            float a = A[i];
            m0 += a; m1 = fmaf(a, a, m1);
            float tt = a * Gv[i];
            m2 += tt; m5 = fmaf(tt, tt, m5); m3 = fmaf(tt, Gv[i], m3); m4 = fmaf(tt, Bv[i], m4);
        }
        m0=wredf(m0); m1=wredf(m1); m2=wredf(m2); m3=wredf(m3); m4=wredf(m4); m5=wredf(m5);
        if (p == 0){
            lmd[cur][g][0]=m0; lmd[cur][g][1]=m1; lmd[cur][g][2]=m2;
            lmd[cur][g][3]=m3; lmd[cur][g][4]=m4; lmd[cur][g][5]=m5;
        }
        __syncthreads();
        float M0 = lmd[cur][0][0]+lmd[cur][1][0]+lmd[cur][2][0]+lmd[cur][3][0];
        float M1 = lmd[cur][0][1]+lmd[cur][1][1]+lmd[cur][2][1]+lmd[cur][3][1];
        float M2 = lmd[cur][0][2]+lmd[cur][1][2]+lmd[cur][2][2]+lmd[cur][3][2];
        float M3 = lmd[cur][0][3]+lmd[cur][1][3]+lmd[cur][2][3]+lmd[cur][3][3];
        float M4 = lmd[cur][0][4]+lmd[cur][1][4]+lmd[cur][2][4]+lmd[cur][3][4];
        float M5 = lmd[cur][0][5]+lmd[cur][1][5]+lmd[cur][2][5]+lmd[cur][3][5];
        float meanA = M0*INV;
        float varA  = M1*INV - meanA*meanA;
        float inv1 = rsqrtf(varA + LN_EPS);
        float sum_sf = inv1*(M2 - meanA*Cg) + Cb;
        float ssq_sf = inv1*inv1*(M5 - 2.f*meanA*M3 + meanA*meanA*Cg2)
                     + 2.f*inv1*(M4 - meanA*Cgb) + Cb2;
        float invr = 1.f / lrA[l];
        float mean_sf = sum_sf*INV;
        float var_sf  = ssq_sf*INV - mean_sf*mean_sf;
        float mean_nam = mean_sf * invr;
        float var_nam  = var_sf * invr * invr;
        float inv2 = rsqrtf(var_nam + LN_EPS);
        float nal = 0.f;
        #pragma unroll
        for (int i = 0; i < 16; i++){
            float sf = fmaf((A[i]-meanA)*inv1, Gv[i], Bv[i]);
            float nm = sf*invr;
            float elem = fmaf((nm-mean_nam)*inv2, NGv[i], NBv[i]);
            nal = fmaf(lnqall[l][g*16+i], elem, nal);
        }
        lnaAll[l][g][p] = nal;
    }
    __syncthreads();   // lnaAll complete

    // ---- epilogue: out-LN parallel across waves (2 rows each) ----
    {
        float nagr = na_g[p], nabr = na_b[p];
        #pragma unroll
        for (int s = 0; s < 2; s++){
            int l = 2*g + s;
            float nt = lnaAll[l][0][p]+lnaAll[l][1][p]+lnaAll[l][2][p]+lnaAll[l][3][p];
            float s1 = wredf(nt), s2 = wredf(nt*nt);
            float mu = s1*(1.f/64.f);
            float va = s2*(1.f/64.f) - mu*mu;
            out[(row0+l)*64 + p] = fmaf((nt-mu)*rsqrtf(va+LN_EPS), nagr, nabr);
        }
    }
    // ---- std: per-block atomics + completion counter ----
    if (t == 0){
        double S  = qpart[0][0]+qpart[1][0]+qpart[2][0]+qpart[3][0];
        double S2 = qpart[0][1]+qpart[1][1]+qpart[2][1]+qpart[3][1];
        atomicAdd(&qstats[0], S);
        atomicAdd(&qstats[1], S2);
        __threadfence();
        unsigned int old = atomicAdd(cnt, 1u);
        if (old == (unsigned int)(B_*C_ - 1)){
            __threadfence();
            double sD  = *((volatile double*)&qstats[0]);
            double sqD = *((volatile double*)&qstats[1]);
            const double N = (double)(B_*L_*D_);
            double var = (sqD - sD*sD/N) / (N - 1.0);
            out[outIdx] = (float)sqrt(var > 0.0 ? var : 0.0);
        }
    }
}

// ================= fallback path (small workspace): old kernels =================
__global__ __launch_bounds__(256) void k0_qzv(
    const float* __restrict__ X,
    const float* __restrict__ Wq, const float* __restrict__ bq,
    const float* __restrict__ Wk, const float* __restrict__ bk,
    const float* __restrict__ Wv, const float* __restrict__ bv,
    float* __restrict__ Q, float* __restrict__ Z, float* __restrict__ V,
    double* __restrict__ qstats)
{
    __shared__ float sW[3][IN_*D_];
    __shared__ float sx[4][IN_];
    int t = threadIdx.x;
    if (blockIdx.x == 0 && t < 2) qstats[t] = 0.0;
    for (int i = t; i < IN_*D_; i += 256){ sW[0][i]=Wq[i]; sW[1][i]=Wk[i]; sW[2][i]=Wv[i]; }
    int p = t & 63, lr = t >> 6;
    float bqv = bq[p], bkv = bk[p], bvv = bv[p];
    for (int it = 0; it < 4; ++it){
        int r0 = blockIdx.x*16 + it*4;
        __syncthreads();
        for (int i = t; i < 4*IN_; i += 256)
            sx[i>>6][i&63] = X[(size_t)(r0 + (i>>6))*IN_ + (i&63)];
        __syncthreads();
        size_t row = r0 + lr;
        float aq = bqv, ak = bkv, av = bvv;
        #pragma unroll
        for (int i = 0; i < IN_; i++){
            float x = sx[lr][i];
            aq = fmaf(x, sW[0][i*D_+p], aq);
            ak = fmaf(x, sW[1][i*D_+p], ak);
            av = fmaf(x, sW[2][i*D_+p], av);
        }
        Q[row*D_+p] = aq > 0.f ? aq : (expf(aq)-1.f);
        Z[row*D_+p] = ak > 0.f ? ak : (expf(ak)-1.f);
        V[row*D_+p] = av;
    }
}

__global__ __launch_bounds__(256) void k1_prompt(
    const float* __restrict__ Pm, const float* __restrict__ Sm,
    const float* __restrict__ Wk, const float* __restrict__ bk,
    const float* __restrict__ Wv, const float* __restrict__ bv,
    const float* __restrict__ z_g, const float* __restrict__ z_b,
    const float* __restrict__ s_g, const float* __restrict__ s_b,
    const float* __restrict__ nam_g, const float* __restrict__ nam_b,
    const int* __restrict__ user_id,
    const float* __restrict__ prev_z_buf, const float* __restrict__ prev_s_buf,
    float* __restrict__ Pz, float* __restrict__ Ps, float* __restrict__ prevLN)
{
    __shared__ float sz[LP_][D_], sv[LP_][D_];
    __shared__ double lds[4][2];
    __shared__ float sca[1];
    int blk = blockIdx.x; int b = blk & (B_-1); int path = blk >> 4;
    int t = threadIdx.x, g = t >> 6, p = t & 63;
    const float* Xs = (path ? Sm : Pm) + (size_t)b*LP_*IN_;
    for (int idx = t; idx < 2*LP_*D_; idx += 256){
        int which = idx >> 9;
        int j = (idx >> 6) & 7;
        int d = idx & 63;
        const float* W = which ? Wv : Wk;
        float acc = which ? bv[d] : bk[d];
        const float* xr = Xs + j*IN_;
        #pragma unroll
        for (int i = 0; i < IN_; i++) acc = fmaf(xr[i], W[i*D_+d], acc);
        if (!which) acc = acc > 0.f ? acc : (expf(acc)-1.f);
        if (which) sv[j][d] = acc; else sz[j][d] = acc;
    }
    __syncthreads();
    if (t < 64){
        float zc = 0.f;
        #pragma unroll
        for (int j = 0; j < LP_; j++) zc += sz[j][t];
        double s1 = wredd((double)zc), s2 = wredd((double)zc*(double)zc);
        float mz = (float)(s1*(1.0/64));
        float vz = (float)(s2*(1.0/64) - (s1*(1.0/64))*(s1*(1.0/64)));
        float zf = fmaf((zc-mz)*rsqrtf(vz+LN_EPS), z_g[t], z_b[t]);
        if (path == 0){ Pz[b*D_+t] = zf; }
        else {
            int uid = user_id[b];
            float pz = prev_z_buf[(size_t)uid*D_+t] + zf;
            float rr = wredf(pz*pz);
            if (t == 0) sca[0] = fmaxf(sqrtf(rr), 1e-8f) + EPSF;
        }
    }
    float sc[16];
    #pragma unroll
    for (int i = 0; i < 16; i++){
        int d = g*16 + i; float a = 0.f;
        #pragma unroll
        for (int j = 0; j < LP_; j++) a = fmaf(sz[j][d], sv[j][p], a);
        sc[i] = a;
    }
    double m0 = 0, m1 = 0;
    #pragma unroll
    for (int i = 0; i < 16; i++){ double a = sc[i]; m0 += a; m1 += a*a; }
    m0 = wredd(m0); m1 = wredd(m1);
    __syncthreads();
    if (p == 0){ lds[g][0] = m0; lds[g][1] = m1; }
    __syncthreads();
    m0 = lds[0][0]+lds[1][0]+lds[2][0]+lds[3][0];
    m1 = lds[0][1]+lds[1][1]+lds[2][1]+lds[3][1];
    double mean1 = m0*(1.0/4096.0);
    double var1 = m1*(1.0/4096.0) - mean1*mean1;
    float inv1 = rsqrtf((float)var1 + LN_EPS);
    float mean1f = (float)mean1;
    float sl[16];
    #pragma unroll
    for (int i = 0; i < 16; i++){
        int e = (g*16+i)*D_ + p;
        sl[i] = fmaf((sc[i]-mean1f)*inv1, s_g[e], s_b[e]);
    }
    if (path == 0){
        #pragma unroll
        for (int i = 0; i < 16; i++) Ps[(size_t)b*4096 + (g*16+i)*D_ + p] = sl[i];
        return;
    }
    int uid = user_id[b];
    float denom = sca[0];
    float pn[16]; double n0 = 0, n1 = 0;
    #pragma unroll
    for (int i = 0; i < 16; i++){
        int e = (g*16+i)*D_ + p;
        float ps = prev_s_buf[(size_t)uid*4096 + e] + sl[i];
        float v = ps / denom;
        pn[i] = v; n0 += v; n1 += (double)v*(double)v;
    }
    n0 = wredd(n0); n1 = wredd(n1);
    __syncthreads();
    if (p == 0){ lds[g][0] = n0; lds[g][1] = n1; }
    __syncthreads();
    n0 = lds[0][0]+lds[1][0]+lds[2][0]+lds[3][0];
    n1 = lds[0][1]+lds[1][1]+lds[2][1]+lds[3][1];
    double meanp = n0*(1.0/4096.0);
    double varp = n1*(1.0/4096.0) - meanp*meanp;
    float invp = rsqrtf((float)varp + LN_EPS);
    float meanpf = (float)meanp;
    #pragma unroll
    for (int i = 0; i < 16; i++){
        int e = (g*16+i)*D_ + p;
        prevLN[(size_t)b*4096 + e] = fmaf((pn[i]-meanpf)*invp, nam_g[e], nam_b[e]);
    }
}

__global__ __launch_bounds__(256) void k2_chunks(
    const float* __restrict__ Z, const float* __restrict__ V,
    float* __restrict__ spart, float* __restrict__ zpart, int C_, int LC_)
{
    int wg = blockIdx.x; int b = wg / C_, c = wg - b*C_;
    int t = threadIdx.x, g = t >> 6, p = t & 63;
    __shared__ float lz[64], lv[64];
    float acc[16];
    #pragma unroll
    for (int i = 0; i < 16; i++) acc[i] = 0.f;
    float zacc = 0.f;
    for (int l = 0; l < LC_; l++){
        size_t row = (size_t)b*L_ + c*LC_ + l;
        __syncthreads();
        if (t < 64) lz[t] = Z[row*64 + t];
        else if (t < 128) lv[t-64] = V[row*64 + (t-64)];
        __syncthreads();
        float v = lv[p];
        #pragma unroll
        for (int i = 0; i < 16; i++) acc[i] = fmaf(lz[g*16+i], v, acc[i]);
        if (t < 64) zacc += lz[t];
    }
    size_t base = ((size_t)wg) << 12;
    #pragma unroll
    for (int i = 0; i < 16; i++) spart[base + (g*16+i)*64 + p] = acc[i];
    if (t < 64) zpart[(size_t)wg*64 + t] = zacc;
}

__global__ __launch_bounds__(256) void k3_serial(
    float* __restrict__ spart, float* __restrict__ zpart, int C_)
{
    int id = blockIdx.x*256 + threadIdx.x;
    const int NS = B_*4096;
    if (id < NS){
        int b = id >> 12;
        int e = id & 4095;
        float run = 0.f;
        for (int c = 0; c < C_; ++c){
            float* ptr = spart + (((size_t)(b*C_+c)) << 12) + e;
            float tv = *ptr; *ptr = run; run += tv;
        }
    } else if (id < NS + B_*64){
        int k = id - NS;
        int b = k >> 6, d = k & 63;
        float run = 0.f;
        for (int c = 0; c < C_; ++c){
            float* ptr = zpart + (size_t)(b*C_+c)*64 + d;
            float tv = *ptr; *ptr = run; run += tv;
        }
    }
}

__global__ __launch_bounds__(256) void k4_main(
    const float* __restrict__ Q, const float* __restrict__ Z, const float* __restrict__ V,
    const float* __restrict__ spart, const float* __restrict__ zpart,
    const float* __restrict__ Pz, const float* __restrict__ Ps,
    const float* __restrict__ prevLN,
    const float* __restrict__ z_g, const float* __restrict__ z_b,
    const float* __restrict__ s_g, const float* __restrict__ s_b,
    const float* __restrict__ nam_g, const float* __restrict__ nam_b,
    const float* __restrict__ na_g, const float* __restrict__ na_b,
    float* __restrict__ out, double* qstats, int C_, int LC_)
{
    int wg = blockIdx.x; int b = wg / C_, c = wg - b*C_;
    int t = threadIdx.x, g = t >> 6, p = t & 63;
    __shared__ float lz[2][64], lv[2][64], lqb[2][64], lnq[2][64];
    __shared__ float lna[2][4][64];
    __shared__ float lmd[2][4][6];
    __shared__ float lcs[4][5];
    __shared__ float lr[2];
    __shared__ float lPz[64];
    float A[16], Gv[16], Bv[16], NGv[16], NBv[16];
    size_t sbase = ((size_t)wg) << 12;
    size_t bbase = ((size_t)b) << 12;
    size_t row0 = (size_t)b*L_ + (size_t)c*LC_;
    if (g == 1) gl_lds4(Q + row0*64 + p, &lqb[0][0]);
    else if (g == 2) gl_lds4(Z + row0*64 + p, &lz[0][0]);
    else if (g == 3) gl_lds4(V + row0*64 + p, &lv[0][0]);
    #pragma unroll
    for (int i = 0; i < 16; i++){
        int e = (g*16+i)*64 + p;
        A[i]   = spart[sbase + e];
        Gv[i]  = s_g[e];
        Bv[i]  = s_b[e] + Ps[bbase + e];
        NGv[i] = nam_g[e];
        NBv[i] = nam_b[e] + prevLN[bbase + e];
    }
    float cs0=0,cs1=0,cs2=0,cs3=0,cs4=0;
    #pragma unroll
    for (int i = 0; i < 16; i++){
        float gd = Gv[i], bd = Bv[i];
        cs0 += gd; cs1 += gd*gd; cs2 += bd; cs3 += bd*bd; cs4 += gd*bd;
    }
    cs0=wredf(cs0); cs1=wredf(cs1); cs2=wredf(cs2); cs3=wredf(cs3); cs4=wredf(cs4);
    if (p == 0){ lcs[g][0]=cs0; lcs[g][1]=cs1; lcs[g][2]=cs2; lcs[g][3]=cs3; lcs[g][4]=cs4; }
    float zc=0.f, zgr=0.f, zbr=0.f, nagr=0.f, nabr=0.f;
    if (g == 0){
        zc = zpart[(size_t)wg*64 + p];
        lPz[p] = Pz[b*64 + p];
        zgr = z_g[p]; zbr = z_b[p];
    }
    if (g == 3){ nagr = na_g[p]; nabr = na_b[p]; }
    __syncthreads();
    float Cg  = lcs[0][0]+lcs[1][0]+lcs[2][0]+lcs[3][0];
    float Cg2 = lcs[0][1]+lcs[1][1]+lcs[2][1]+lcs[3][1];
    float Cb  = lcs[0][2]+lcs[1][2]+lcs[2][2]+lcs[3][2];
    float Cb2 = lcs[0][3]+lcs[1][3]+lcs[2][3]+lcs[3][3];
    float Cgb = lcs[0][4]+lcs[1][4]+lcs[2][4]+lcs[3][4];

    double qsum = 0.0, qsq = 0.0;
    const float INV = 1.f/4096.f;
    for (int ll = 0; ll < LC_; ++ll){
        int cur = ll & 1, nxt = cur ^ 1, prv = cur ^ 1;
        size_t row = row0 + ll;
        if (ll + 1 < LC_){
            if (g == 1) gl_lds4(Q + (row+1)*64 + p, &lqb[nxt][0]);
            else if (g == 2) gl_lds4(Z + (row+1)*64 + p, &lz[nxt][0]);
            else if (g == 3) gl_lds4(V + (row+1)*64 + p, &lv[nxt][0]);
        }
        if (g == 0){
            float zl = lz[cur][p]; zc += zl;
            float s1 = wredf(zc), s2 = wredf(zc*zc);
            float mz = s1*(1.f/64.f);
            float vz = s2*(1.f/64.f) - mz*mz;
            float zf = fmaf((zc-mz)*rsqrtf(vz+LN_EPS), zgr, zbr) + lPz[p];
            float rr = wredf(zf*zf);
            if (p == 0) lr[cur] = fmaxf(sqrtf(rr), 1e-8f);
            float qvv = lqb[cur][p];
            float qn = qvv / fmaxf(zf, 1e-6f);
            qsum += (double)qn; qsq += (double)qn*(double)qn;
        }
        if (g == 1){
            float qvv = lqb[cur][p];
            float qq = wredf(qvv*qvv);
            lnq[cur][p] = qvv / fmaxf(sqrtf(qq), 1e-8f);
        }
        float m0=0,m1=0,m2=0,m3=0,m4=0,m5=0;
        float vp = lv[cur][p];
        #pragma unroll
        for (int i = 0; i < 16; i++){
            A[i] = fmaf(lz[cur][g*16+i], vp, A[i]);
            float a = A[i];
            m0 += a; m1 = fmaf(a, a, m1);
            float tt = a * Gv[i];
            m2 += tt; m5 = fmaf(tt, tt, m5); m3 = fmaf(tt, Gv[i], m3); m4 = fmaf(tt, Bv[i], m4);
        }
        m0=wredf(m0); m1=wredf(m1); m2=wredf(m2); m3=wredf(m3); m4=wredf(m4); m5=wredf(m5);
        if (p == 0){
            lmd[cur][g][0]=m0; lmd[cur][g][1]=m1; lmd[cur][g][2]=m2;
            lmd[cur][g][3]=m3; lmd[cur][g][4]=m4; lmd[cur][g][5]=m5;
        }
        __syncthreads();
        float M0 = lmd[cur][0][0]+lmd[cur][1][0]+lmd[cur][2][0]+lmd[cur][3][0];
        float M1 = lmd[cur][0][1]+lmd[cur][1][1]+lmd[cur][2][1]+lmd[cur][3][1];
        float M2 = lmd[cur][0][2]+lmd[cur][1][2]+lmd[cur][2][2]+lmd[cur][3][2];
        float M3 = lmd[cur][0][3]+lmd[cur][1][3]+lmd[cur][2][3]+lmd[cur][3][3];
        float M4 = lmd[cur][0][4]+lmd[cur][1][4]+lmd[cur][2][4]+lmd[cur][3][4];
        float M5 = lmd[cur][0][5]+lmd[cur][1][5]+lmd[cur][2][5]+lmd[cur][3][5];
        float meanA = M0*INV;
        float varA  = M1*INV - meanA*meanA;
        float inv1 = rsqrtf(varA + LN_EPS);
        float sum_sf = inv1*(M2 - meanA*Cg) + Cb;
        float ssq_sf = inv1*inv1*(M5 - 2.f*meanA*M3 + meanA*meanA*Cg2)
                     + 2.f*inv1*(M4 - meanA*Cgb) + Cb2;
        float r = lr[cur];
        float invr = 1.f/r;
        float mean_sf = sum_sf*INV;
        float var_sf  = ssq_sf*INV - mean_sf*mean_sf;
        float mean_nam = mean_sf * invr;
        float var_nam  = var_sf * invr * invr;
        float inv2 = rsqrtf(var_nam + LN_EPS);
        float nal = 0.f;
        #pragma unroll
        for (int i = 0; i < 16; i++){
            float sf = fmaf((A[i]-meanA)*inv1, Gv[i], Bv[i]);
            float nm = sf*invr;
            float elem = fmaf((nm-mean_nam)*inv2, NGv[i], NBv[i]);
            nal = fmaf(lnq[cur][g*16+i], elem, nal);
        }
        lna[cur][g][p] = nal;
        if (g == 3 && ll > 0){
            float nt = lna[prv][0][p]+lna[prv][1][p]+lna[prv][2][p]+lna[prv][3][p];
            float s1 = wredf(nt), s2 = wredf(nt*nt);
            float mu = s1*(1.f/64.f);
            float va = s2*(1.f/64.f) - mu*mu;
            out[(row-1)*64 + p] = fmaf((nt-mu)*rsqrtf(va+LN_EPS), nagr, nabr);
        }
    }
    __syncthreads();
    if (g == 3){
        int lastc = (LC_-1) & 1;
        float nt = lna[lastc][0][p]+lna[lastc][1][p]+lna[lastc][2][p]+lna[lastc][3][p];
        float s1 = wredf(nt), s2 = wredf(nt*nt);
        float mu = s1*(1.f/64.f);
        float va = s2*(1.f/64.f) - mu*mu;
        out[(row0+LC_-1)*64 + p] = fmaf((nt-mu)*rsqrtf(va+LN_EPS), nagr, nabr);
    }
    if (g == 0){
        double s = wredd(qsum), s2 = wredd(qsq);
        if (p == 0){
            atomicAdd(&qstats[0], s);
            atomicAdd(&qstats[1], s2);
        }
    }
}

__global__ void k5_std(const double* __restrict__ qstats, float* __restrict__ out, int idx){
    if (threadIdx.x == 0 && blockIdx.x == 0){
        double s = qstats[0], sq = qstats[1];
        const double N = (double)(B_*L_*D_);
        double var = (sq - s*s/N) / (N - 1.0);
        out[idx] = (float)sqrt(var > 0.0 ? var : 0.0);
    }
}

extern "C" void kernel_launch(void* const* d_in, const int* in_sizes, int n_in,
                              void* d_out, int out_size, void* d_ws, size_t ws_size,
                              hipStream_t stream)
{
    (void)in_sizes; (void)n_in;
    const int*   user_id    = (const int*)d_in[0];
    const float* seqs       = (const float*)d_in[1];
    const float* Pm         = (const float*)d_in[2];
    const float* Sm         = (const float*)d_in[3];
    const float* Wq         = (const float*)d_in[4];
    const float* bq         = (const float*)d_in[5];
    const float* Wk         = (const float*)d_in[6];
    const float* bk         = (const float*)d_in[7];
    const float* Wv         = (const float*)d_in[8];
    const float* bv         = (const float*)d_in[9];
    const float* z_g        = (const float*)d_in[10];
    const float* z_b        = (const float*)d_in[11];
    const float* s_g        = (const float*)d_in[12];
    const float* s_b        = (const float*)d_in[13];
    const float* nam_g      = (const float*)d_in[14];
    const float* nam_b      = (const float*)d_in[15];
    const float* na_g       = (const float*)d_in[16];
    const float* na_b       = (const float*)d_in[17];
    const float* prev_z_buf = (const float*)d_in[18];
    const float* prev_s_buf = (const float*)d_in[19];
    float* out = (float*)d_out;

    char* w = (char*)d_ws;
    double* qstats = (double*)w;                     // 16 B
    unsigned int* cnt = (unsigned int*)(w + 16);     // 4 B (pad to 32)
    float* Q  = (float*)(w + 32);                    // 524288
    float* Zb = Q  + 524288;
    float* Vb = Zb + 524288;
    float* Pz = Vb + 524288;                         // 1024
    float* Ps = Pz + 1024;                           // 65536
    float* prevLN = Ps + 65536;                      // 65536
    float* spart  = prevLN + 65536;                  // 16*C*4096
    size_t fixedBytes = 32 + (size_t)(3*524288 + 1024 + 2*65536)*4;
    int C = 64;
    while (C > 1 && fixedBytes + (size_t)16*C*(4096+64)*4 > ws_size) C >>= 1;
    int LC = 512 / C;
    float* zpart = spart + (size_t)16*C*4096;

    if (C == 64){
        k0k1<8,2><<<544, 256, 0, stream>>>(seqs, Wq, bq, Wk, bk, Wv, bv,
                                           Q, Zb, Vb, spart, zpart, qstats, cnt,
                                           Pm, Sm, z_g, z_b, s_g, s_b, nam_g, nam_b,
                                           user_id, prev_z_buf, prev_s_buf,
                                           Pz, Ps, prevLN);
        k3_scan<64><<<(16*4096 + 16*64 + 255)/256, 256, 0, stream>>>(spart, zpart);
        k4_fused<<<16*64, 256, 0, stream>>>(Q, Zb, Vb, spart, zpart, Pz, Ps, prevLN,
                                            z_g, z_b, s_g, s_b, nam_g, nam_b, na_g, na_b,
                                            out, qstats, cnt, out_size - 1);
    } else {
        k0_qzv<<<512, 256, 0, stream>>>(seqs, Wq, bq, Wk, bk, Wv, bv, Q, Zb, Vb, qstats);
        k1_prompt<<<32, 256, 0, stream>>>(Pm, Sm, Wk, bk, Wv, bv, z_g, z_b, s_g, s_b,
                                          nam_g, nam_b, user_id, prev_z_buf, prev_s_buf,
                                          Pz, Ps, prevLN);
        k2_chunks<<<16*C, 256, 0, stream>>>(Zb, Vb, spart, zpart, C, LC);
        k3_serial<<<(16*4096 + 16*64 + 255)/256, 256, 0, stream>>>(spart, zpart, C);
        k4_main<<<16*C, 256, 0, stream>>>(Q, Zb, Vb, spart, zpart, Pz, Ps, prevLN,
                                          z_g, z_b, s_g, s_b, nam_g, nam_b, na_g, na_b,
                                          out, qstats, C, LC);
        k5_std<<<1, 64, 0, stream>>>(qstats, out, out_size - 1);
    }
}